// Round 1
// baseline (9416.720 us; speedup 1.0000x reference)
//
#include <hip/hip_runtime.h>
#include <hip/hip_bf16.h>

#define BB 2
#define TT 2048
#define DD 1024
#define HH 8
#define DKk 64
#define HKk 512
#define RR 64
#define DFFf 4096
#define BTt 4096  // BB*TT

// ---------- flag-aware load/store (0 = f32 buffers, 1 = bf16 buffers) ----------
__device__ __forceinline__ float ldin(const void* p, size_t i, int bf) {
  if (bf) {
    unsigned short v = ((const unsigned short*)p)[i];
    union { unsigned u; float f; } c; c.u = ((unsigned)v) << 16;
    return c.f;
  }
  return ((const float*)p)[i];
}

__device__ __forceinline__ void stout(void* p, size_t i, float v, int bf) {
  if (bf) {
    union { float f; unsigned u; } c; c.f = v;
    unsigned r = (c.u + 0x7fffu + ((c.u >> 16) & 1u)) >> 16;  // RNE
    ((unsigned short*)p)[i] = (unsigned short)r;
  } else {
    ((float*)p)[i] = v;
  }
}

__device__ __forceinline__ float sigm(float x) { return 1.f / (1.f + expf(-x)); }

// ---------- dtype detection ----------
// If the buffer is bf16 pairs, the low 16 bits of each u32 word are a bf16 value
// from N(0,1): exponent field in [100,140] essentially always. If f32, the low
// 16 bits are mantissa bits (uniform): only ~16% land in that window.
__global__ void kdetect(const unsigned* __restrict__ xw, int* __restrict__ flag) {
  __shared__ int cnt;
  if (threadIdx.x == 0) cnt = 0;
  __syncthreads();
  int c = 0;
  for (int i = threadIdx.x; i < 1024; i += 256) {
    unsigned lo = xw[i] & 0xffffu;
    unsigned e = (lo >> 7) & 0xffu;
    if (e >= 100 && e <= 140) c++;
  }
  atomicAdd(&cnt, c);
  __syncthreads();
  if (threadIdx.x == 0) flag[0] = (cnt > 600) ? 1 : 0;
}

// ---------- RMS norm over 1024 cols ----------
__global__ __launch_bounds__(256) void krms(const void* __restrict__ x, int xraw,
                                            const void* __restrict__ w,
                                            float* __restrict__ out,
                                            const int* __restrict__ flagp) {
  int bf = *flagp;
  int xbf = xraw ? bf : 0;
  size_t row = blockIdx.x;
  __shared__ float red[4];
  float vals[4];
  float s = 0.f;
#pragma unroll
  for (int i = 0; i < 4; i++) {
    vals[i] = ldin(x, row * DD + threadIdx.x + i * 256, xbf);
    s += vals[i] * vals[i];
  }
#pragma unroll
  for (int off = 32; off; off >>= 1) s += __shfl_xor(s, off);
  if ((threadIdx.x & 63) == 0) red[threadIdx.x >> 6] = s;
  __syncthreads();
  float tot = red[0] + red[1] + red[2] + red[3];
  float sc = rsqrtf(tot * (1.f / DD) + 1e-6f);
#pragma unroll
  for (int i = 0; i < 4; i++)
    out[row * DD + threadIdx.x + i * 256] =
        vals[i] * sc * ldin(w, threadIdx.x + i * 256, bf);
}

// ---------- causal depthwise conv (KW=4) + bias + SiLU ----------
__global__ __launch_bounds__(256) void kconv(const float* __restrict__ hin,
                                             const void* __restrict__ cw,
                                             const void* __restrict__ cb,
                                             float* __restrict__ hout,
                                             const int* __restrict__ flagp) {
  int bf = *flagp;
  size_t i = (size_t)blockIdx.x * 256 + threadIdx.x;
  int d = (int)(i & 1023);
  int bt = (int)(i >> 10);
  int b = bt >> 11, t = bt & 2047;
  float acc = ldin(cb, d, bf);
#pragma unroll
  for (int j = 0; j < 4; j++) {
    int tt = t - 3 + j;
    if (tt >= 0) acc += hin[(((size_t)(b * TT + tt)) << 10) + d] * ldin(cw, d * 4 + j, bf);
  }
  hout[i] = acc * sigm(acc);  // SiLU
}

// ---------- generic tiled GEMM: C = epi(act(A*B + bias)) ----------
// A: [M,K] (raw-or-ws), B: [K,N] raw input, bias raw or null.
// act: 0 none, 1 silu, 2 sigmoid. epi: C = C*mulp + addp (optional).
__global__ __launch_bounds__(256) void kgemm(const void* __restrict__ A, int Araw,
                                             const void* __restrict__ Bm, int Braw,
                                             const void* __restrict__ bias,
                                             float* __restrict__ C,
                                             int M, int N, int K, int act,
                                             const float* __restrict__ mulp,
                                             const void* __restrict__ addp, int addraw,
                                             const int* __restrict__ flagp) {
  int bf = *flagp;
  int abf = Araw ? bf : 0, bbf = Braw ? bf : 0;
  __shared__ __align__(16) float As[16][64];
  __shared__ __align__(16) float Bs[16][64];
  int tid = threadIdx.x;
  int tx = tid & 15, ty = tid >> 4;
  int row0 = blockIdx.y * 64, col0 = blockIdx.x * 64;
  float acc[4][4] = {};
  for (int k0 = 0; k0 < K; k0 += 16) {
#pragma unroll
    for (int l = 0; l < 4; l++) {
      int e = tid * 4 + l;
      int m = e >> 4, kk = e & 15;
      int gr = row0 + m;
      As[kk][m] = (gr < M) ? ldin(A, (size_t)gr * K + k0 + kk, abf) : 0.f;
    }
#pragma unroll
    for (int l = 0; l < 4; l++) {
      int e = tid + l * 256;
      int kk = e >> 6, n = e & 63;
      int gc = col0 + n;
      Bs[kk][n] = (gc < N) ? ldin(Bm, (size_t)(k0 + kk) * N + gc, bbf) : 0.f;
    }
    __syncthreads();
#pragma unroll
    for (int kk = 0; kk < 16; kk++) {
      float4 av = *(const float4*)&As[kk][ty * 4];
      float4 bv = *(const float4*)&Bs[kk][tx * 4];
      float a[4] = {av.x, av.y, av.z, av.w};
      float b[4] = {bv.x, bv.y, bv.z, bv.w};
#pragma unroll
      for (int i = 0; i < 4; i++)
#pragma unroll
        for (int j = 0; j < 4; j++) acc[i][j] += a[i] * b[j];
    }
    __syncthreads();
  }
#pragma unroll
  for (int i = 0; i < 4; i++) {
    int r = row0 + ty * 4 + i;
    if (r >= M) continue;
#pragma unroll
    for (int j = 0; j < 4; j++) {
      int cc = col0 + tx * 4 + j;
      if (cc >= N) continue;
      float vv = acc[i][j];
      if (bias) vv += ldin(bias, cc, bf);
      if (act == 1) vv = vv * sigm(vv);
      else if (act == 2) vv = sigm(vv);
      size_t idx = (size_t)r * N + cc;
      if (mulp) vv *= mulp[idx];
      if (addp) vv += ldin(addp, idx, addraw ? bf : 0);
      C[idx] = vv;
    }
  }
}

// ---------- L2 normalize rows of 64 (q, k): x /= (||x|| + 1e-6) ----------
__global__ __launch_bounds__(256) void kl2norm(float* __restrict__ x) {
  int lane = threadIdx.x & 63;
  size_t r = (size_t)blockIdx.x * 4 + (threadIdx.x >> 6);
  float vv = x[r * 64 + lane];
  float s = vv * vv;
#pragma unroll
  for (int off = 32; off; off >>= 1) s += __shfl_xor(s, off);
  x[r * 64 + lane] = vv / (sqrtf(s) + 1e-6f);
}

// ---------- headwise RMS norm over dv=64 with weight ----------
__global__ __launch_bounds__(256) void kheadnorm(float* __restrict__ y,
                                                 const void* __restrict__ hw,
                                                 const int* __restrict__ flagp) {
  int bf = *flagp;
  int lane = threadIdx.x & 63;
  size_t r = (size_t)blockIdx.x * 4 + (threadIdx.x >> 6);
  int h = (int)(r & 7);
  float vv = y[r * 64 + lane];
  float s = vv * vv;
#pragma unroll
  for (int off = 32; off; off >>= 1) s += __shfl_xor(s, off);
  y[r * 64 + lane] = vv * rsqrtf(s * (1.f / 64.f) + 1e-6f) * ldin(hw, h * 64 + lane, bf);
}

// ---------- LIF spike scan: computes alpha[BT,HK] and beta[BT,H] ----------
__global__ __launch_bounds__(64) void klif(const float* __restrict__ dr,
                                           const float* __restrict__ ab,
                                           const float* __restrict__ bb,
                                           const void* __restrict__ aspr,
                                           const void* __restrict__ bspr,
                                           float* __restrict__ alpha,
                                           float* __restrict__ beta,
                                           const int* __restrict__ flagp) {
  int bf = *flagp;
  int bh = blockIdx.x;
  int b = bh >> 3, h = bh & 7;
  int lane = threadIdx.x;
  float aspk = ldin(aspr, h * DKk + lane, bf);
  float bspk = ldin(bspr, h * DKk + lane, bf);
  float mem = 0.f;
  for (int t0 = 0; t0 < TT; t0 += 16) {
    float drc[16], abc[16];
#pragma unroll
    for (int i = 0; i < 16; i++) {
      size_t base = ((size_t)(b * TT + t0 + i)) * HKk + h * DKk + lane;
      drc[i] = dr[base];
      abc[i] = ab[base];
    }
    float bbv = (lane < 16) ? bb[((size_t)(b * TT + t0 + lane)) * HH + h] : 0.f;
#pragma unroll
    for (int i = 0; i < 16; i++) {
      mem = 0.9f * mem + drc[i];
      float spike = (mem > 0.5f) ? 1.f : 0.f;
      mem -= 0.5f * spike;
      float r1 = spike, r2 = spike * bspk;
#pragma unroll
      for (int off = 32; off; off >>= 1) {
        r1 += __shfl_xor(r1, off);
        r2 += __shfl_xor(r2, off);
      }
      float bbi = __shfl(bbv, i);
      int active = (r1 > 0.f);
      float al = active ? sigm(abc[i] + aspk * spike) : 1.f;
      float bt = active ? sigm(bbi + r2) : 0.f;
      size_t base = ((size_t)(b * TT + t0 + i)) * HKk + h * DKk + lane;
      alpha[base] = al;
      if (lane == 0) beta[((size_t)(b * TT + t0 + i)) * HH + h] = bt;
    }
  }
}

// ---------- gated delta-rule sequential scan ----------
// One wave per (b,h); lane = v-column; S[k][lane] in 64 VGPRs.
__global__ __launch_bounds__(64) void kscan(const float* __restrict__ q,
                                            const float* __restrict__ k,
                                            const float* __restrict__ v,
                                            const float* __restrict__ alpha,
                                            const float* __restrict__ beta,
                                            float* __restrict__ y) {
  int bh = blockIdx.x;
  int b = bh >> 3, h = bh & 7;
  int lane = threadIdx.x;
  float S[64];
#pragma unroll
  for (int i = 0; i < 64; i++) S[i] = 0.f;
  __shared__ float2 sAK[8][64];  // (alpha, k)
  __shared__ float2 sKQ[8][64];  // (k, q)
  __shared__ float sv[8][64];
  __shared__ float sb[8];
  for (int t0 = 0; t0 < TT; t0 += 8) {
#pragma unroll
    for (int i = 0; i < 8; i++) {
      size_t base = ((size_t)(b * TT + t0 + i)) * HKk + h * DKk;
      float kv = k[base + lane];
      sAK[i][lane] = make_float2(alpha[base + lane], kv);
      sKQ[i][lane] = make_float2(kv, q[base + lane]);
      sv[i][lane] = v[base + lane];
    }
    if (lane < 8) sb[lane] = beta[((size_t)(b * TT + t0 + lane)) * HH + h];
    __syncthreads();
#pragma unroll 1
    for (int i = 0; i < 8; i++) {
      float pr[4] = {0.f, 0.f, 0.f, 0.f};
#pragma unroll
      for (int kk = 0; kk < 64; kk++) {
        float2 ak = sAK[i][kk];
        S[kk] *= ak.x;
        pr[kk & 3] += ak.y * S[kk];
      }
      float pred = (pr[0] + pr[1]) + (pr[2] + pr[3]);
      float c = sb[i] * (sv[i][lane] - pred);
      float ou[4] = {0.f, 0.f, 0.f, 0.f};
#pragma unroll
      for (int kk = 0; kk < 64; kk++) {
        float2 kq = sKQ[i][kk];
        S[kk] += kq.x * c;
        ou[kk & 3] += kq.y * S[kk];
      }
      y[((size_t)(b * TT + t0 + i)) * HKk + h * DKk + lane] =
          (ou[0] + ou[1]) + (ou[2] + ou[3]);
    }
    __syncthreads();
  }
}

// ---------- elementwise a *= b ----------
__global__ __launch_bounds__(256) void kmul(float* __restrict__ a,
                                            const float* __restrict__ b, size_t n) {
  size_t i = (size_t)blockIdx.x * 256 + threadIdx.x;
  if (i < n) a[i] *= b[i];
}

// ---------- final store with dtype flag ----------
__global__ __launch_bounds__(256) void kout(const float* __restrict__ src,
                                            void* __restrict__ dst, size_t n,
                                            const int* __restrict__ flagp) {
  int bf = *flagp;
  size_t i = (size_t)blockIdx.x * 256 + threadIdx.x;
  if (i < n) stout(dst, i, src[i], bf);
}

extern "C" void kernel_launch(void* const* d_in, const int* in_sizes, int n_in,
                              void* d_out, int out_size, void* d_ws, size_t ws_size,
                              hipStream_t stream) {
  const void *x = d_in[0], *norm_in_w = d_in[1], *conv_w = d_in[2], *conv_b = d_in[3],
             *Wq = d_in[4], *Wk = d_in[5], *Wv = d_in[6], *Wo = d_in[7], *Wspike = d_in[8],
             *Wau = d_in[9], *bau = d_in[10], *Wad = d_in[11], *bad_ = d_in[12],
             *asp = d_in[13], *Wbeta = d_in[14], *bbeta = d_in[15], *bsp = d_in[16],
             *hnw = d_in[17], *Wu1 = d_in[18], *bu1 = d_in[19], *Wu2 = d_in[20],
             *bu2 = d_in[21], *ffw = d_in[22], *Wff1 = d_in[23], *Wff3 = d_in[24],
             *Wff2 = d_in[25];
  (void)in_sizes; (void)n_in; (void)out_size; (void)ws_size;

  float* wsf = (float*)d_ws;
  int* flag = (int*)d_ws;
  size_t off = 64;
  auto alloc = [&](size_t n) {
    size_t o = off;
    off += (n + 63) & ~(size_t)63;
    return wsf + o;
  };
  float* h    = alloc((size_t)BTt * DD);
  float* h2   = alloc((size_t)BTt * DD);
  float* q    = alloc((size_t)BTt * HKk);
  float* k    = alloc((size_t)BTt * HKk);
  float* v    = alloc((size_t)BTt * HKk);
  float* dr   = alloc((size_t)BTt * HKk);
  float* ab   = alloc((size_t)BTt * HKk);
  float* bb   = alloc((size_t)BTt * HH);
  float* au   = alloc((size_t)BTt * RR);
  float* alph = alloc((size_t)BTt * HKk);
  float* beta = alloc((size_t)BTt * HH);
  float* yat  = alloc((size_t)BTt * HKk);
  float* u1   = alloc((size_t)BTt * RR);
  float* gate = alloc((size_t)BTt * DD);
  float* y2   = alloc((size_t)BTt * DD);
  float* z    = alloc((size_t)BTt * DD);
  float* f1   = alloc((size_t)1024 * DFFf);
  float* f3   = alloc((size_t)1024 * DFFf);
  float* outf = alloc((size_t)BTt * DD);

  kdetect<<<1, 256, 0, stream>>>((const unsigned*)x, flag);
  krms<<<BTt, 256, 0, stream>>>(x, 1, norm_in_w, h, flag);
  kconv<<<BTt * DD / 256, 256, 0, stream>>>(h, conv_w, conv_b, h2, flag);

  auto gemm = [&](const void* A, int Araw, const void* Bm, const void* bias, float* C,
                  int M, int N, int K, int act, const float* mulp, const void* addp,
                  int addraw) {
    kgemm<<<dim3((N + 63) / 64, (M + 63) / 64), 256, 0, stream>>>(
        A, Araw, Bm, 1, bias, C, M, N, K, act, mulp, addp, addraw, flag);
  };

  gemm(h2, 0, Wq, nullptr, q, BTt, HKk, DD, 0, nullptr, nullptr, 0);
  gemm(h2, 0, Wk, nullptr, k, BTt, HKk, DD, 0, nullptr, nullptr, 0);
  gemm(h2, 0, Wv, nullptr, v, BTt, HKk, DD, 0, nullptr, nullptr, 0);
  gemm(h2, 0, Wspike, nullptr, dr, BTt, HKk, DD, 0, nullptr, nullptr, 0);
  gemm(h2, 0, Wau, bau, au, BTt, RR, DD, 1, nullptr, nullptr, 0);
  gemm(au, 0, Wad, bad_, ab, BTt, HKk, RR, 0, nullptr, nullptr, 0);
  gemm(h2, 0, Wbeta, bbeta, bb, BTt, HH, DD, 0, nullptr, nullptr, 0);

  kl2norm<<<BTt * HH / 4, 256, 0, stream>>>(q);
  kl2norm<<<BTt * HH / 4, 256, 0, stream>>>(k);
  klif<<<BB * HH, 64, 0, stream>>>(dr, ab, bb, asp, bsp, alph, beta, flag);
  kscan<<<BB * HH, 64, 0, stream>>>(q, k, v, alph, beta, yat);
  kheadnorm<<<BTt * HH / 4, 256, 0, stream>>>(yat, hnw, flag);

  gemm(x, 1, Wu1, bu1, u1, BTt, RR, DD, 1, nullptr, nullptr, 0);
  gemm(u1, 0, Wu2, bu2, gate, BTt, DD, RR, 2, nullptr, nullptr, 0);
  gemm(yat, 0, Wo, nullptr, y2, BTt, DD, HKk, 0, gate, x, 1);

  krms<<<BTt, 256, 0, stream>>>(y2, 0, ffw, z, flag);
  for (int s = 0; s < 4; s++) {
    size_t ro = (size_t)s * 1024;
    gemm(z + ro * DD, 0, Wff1, nullptr, f1, 1024, DFFf, DD, 1, nullptr, nullptr, 0);
    gemm(z + ro * DD, 0, Wff3, nullptr, f3, 1024, DFFf, DD, 0, nullptr, nullptr, 0);
    kmul<<<1024 * DFFf / 256, 256, 0, stream>>>(f1, f3, (size_t)1024 * DFFf);
    gemm(f1, 0, Wff2, nullptr, outf + ro * DD, 1024, DD, DFFf, 0, nullptr, y2 + ro * DD, 0);
  }
  kout<<<BTt * DD / 256, 256, 0, stream>>>(outf, d_out, (size_t)BTt * DD, flag);
}

// Round 5
// 3935.768 us; speedup vs baseline: 2.3926x; 2.3926x over previous
//
#include <hip/hip_runtime.h>
#include <hip/hip_bf16.h>

#define BB 2
#define TT 2048
#define DD 1024
#define HH 8
#define HKk 512
#define BTt 4096  // BB*TT

typedef unsigned short u16;
typedef __attribute__((ext_vector_type(8))) short bf16x8;
typedef __attribute__((ext_vector_type(4))) float f32x4;

__device__ __forceinline__ u16 f2bf(float v) {
  union { float f; unsigned u; } c; c.f = v;
  return (u16)((c.u + 0x7fffu + ((c.u >> 16) & 1u)) >> 16);  // RNE
}
__device__ __forceinline__ float bf2f(u16 v) {
  union { unsigned u; float f; } c; c.u = ((unsigned)v) << 16; return c.f;
}
__device__ __forceinline__ float sigm(float x) { return 1.f / (1.f + expf(-x)); }

// ---------- weight transpose + cast: dst_bf16[n*K+k] = src_f32[k*N+n] ----------
__global__ __launch_bounds__(256) void ktrans(const float* __restrict__ src,
                                              u16* __restrict__ dst, int K, int N) {
  __shared__ u16 t[32][33];
  int n0 = blockIdx.x * 32, k0 = blockIdx.y * 32;
  int tx = threadIdx.x & 31, ty0 = threadIdx.x >> 5;
#pragma unroll
  for (int i = 0; i < 32; i += 8)
    t[ty0 + i][tx] = f2bf(src[(size_t)(k0 + ty0 + i) * N + n0 + tx]);
  __syncthreads();
#pragma unroll
  for (int i = 0; i < 32; i += 8)
    dst[(size_t)(n0 + ty0 + i) * K + k0 + tx] = t[tx][ty0 + i];
}

// ---------- RMS norm over 1024 cols (f32 in, f32 weights; obf: bf16 or f32 out) ----------
__global__ __launch_bounds__(256) void krms(const float* __restrict__ x,
                                            const float* __restrict__ w,
                                            void* __restrict__ out, int obf) {
  size_t row = blockIdx.x;
  __shared__ float red[4];
  float vals[4];
  float s = 0.f;
#pragma unroll
  for (int i = 0; i < 4; i++) {
    vals[i] = x[row * DD + threadIdx.x + i * 256];
    s += vals[i] * vals[i];
  }
#pragma unroll
  for (int off = 32; off; off >>= 1) s += __shfl_xor(s, off);
  if ((threadIdx.x & 63) == 0) red[threadIdx.x >> 6] = s;
  __syncthreads();
  float tot = red[0] + red[1] + red[2] + red[3];
  float sc = rsqrtf(tot * (1.f / DD) + 1e-6f);
#pragma unroll
  for (int i = 0; i < 4; i++) {
    size_t idx = row * DD + threadIdx.x + i * 256;
    float vv = vals[i] * sc * w[threadIdx.x + i * 256];
    if (obf) ((u16*)out)[idx] = f2bf(vv);
    else ((float*)out)[idx] = vv;
  }
}

// ---------- causal depthwise conv (KW=4) + bias + SiLU: f32 in -> bf16 out ----------
__global__ __launch_bounds__(256) void kconv(const float* __restrict__ hin,
                                             const float* __restrict__ cw,
                                             const float* __restrict__ cb,
                                             u16* __restrict__ hout) {
  size_t i = (size_t)blockIdx.x * 256 + threadIdx.x;
  int d = (int)(i & 1023);
  int bt = (int)(i >> 10);
  int b = bt >> 11, t = bt & 2047;
  float acc = cb[d];
#pragma unroll
  for (int j = 0; j < 4; j++) {
    int tt = t - 3 + j;
    if (tt >= 0) acc += hin[(((size_t)(b * TT + tt)) << 10) + d] * cw[d * 4 + j];
  }
  hout[i] = f2bf(acc * sigm(acc));
}

// ---------- small f32-compute GEMM: C_f32 = act(A@B + bias); A bf16 (abf=1) or f32 ----------
__global__ __launch_bounds__(256) void kgemm(const void* __restrict__ A, int abf,
                                             const float* __restrict__ Bm,
                                             const float* __restrict__ bias,
                                             float* __restrict__ C,
                                             int M, int N, int K, int act) {
  __shared__ __align__(16) float As[16][64];
  __shared__ __align__(16) float Bs[16][64];
  int tid = threadIdx.x;
  int tx = tid & 15, ty = tid >> 4;
  int row0 = blockIdx.y * 64, col0 = blockIdx.x * 64;
  float acc[4][4] = {};
  for (int k0 = 0; k0 < K; k0 += 16) {
#pragma unroll
    for (int l = 0; l < 4; l++) {
      int e = tid * 4 + l;
      int m = e >> 4, kk = e & 15;
      int gr = row0 + m;
      size_t ai = (size_t)gr * K + k0 + kk;
      As[kk][m] = (gr < M) ? (abf ? bf2f(((const u16*)A)[ai]) : ((const float*)A)[ai]) : 0.f;
    }
#pragma unroll
    for (int l = 0; l < 4; l++) {
      int e = tid + l * 256;
      int kk = e >> 6, n = e & 63;
      int gc = col0 + n;
      Bs[kk][n] = (gc < N) ? Bm[(size_t)(k0 + kk) * N + gc] : 0.f;
    }
    __syncthreads();
#pragma unroll
    for (int kk = 0; kk < 16; kk++) {
      float4 av = *(const float4*)&As[kk][ty * 4];
      float4 bv = *(const float4*)&Bs[kk][tx * 4];
      float a[4] = {av.x, av.y, av.z, av.w};
      float b[4] = {bv.x, bv.y, bv.z, bv.w};
#pragma unroll
      for (int i = 0; i < 4; i++)
#pragma unroll
        for (int j = 0; j < 4; j++) acc[i][j] += a[i] * b[j];
    }
    __syncthreads();
  }
#pragma unroll
  for (int i = 0; i < 4; i++) {
    int r = row0 + ty * 4 + i;
    if (r >= M) continue;
#pragma unroll
    for (int j = 0; j < 4; j++) {
      int cc = col0 + tx * 4 + j;
      if (cc >= N) continue;
      float vv = acc[i][j];
      if (bias) vv += bias[cc];
      if (act == 1) vv = vv * sigm(vv);
      else if (act == 2) vv = sigm(vv);
      C[(size_t)r * N + cc] = vv;
    }
  }
}

// ---------- big MFMA GEMM: C[M,N] = epi(A[M,K]bf16 @ Bt[N,K]bf16^T) ----------
// EPI 0: f32 store. 1: silu where col<silucut, bf16 store.
// 2: f32 store of g1f+acc*g2f. 3: f32 store of f1+acc.
template <int EPI>
__global__ __launch_bounds__(256) void kmfma(
    const u16* __restrict__ A, int lda, const u16* __restrict__ Bt,
    void* __restrict__ C, int ldc, int M, int N, int K,
    const float* __restrict__ g1f, const float* __restrict__ g2f,
    const float* __restrict__ f1, int silucut) {
  __shared__ __align__(16) u16 As[128 * 72];
  __shared__ __align__(16) u16 Bs[128 * 72];
  int tid = threadIdx.x;
  int lane = tid & 63, wv = tid >> 6;
  int m0 = (wv & 1) * 64, n0 = (wv >> 1) * 64;
  int ml = lane & 15, kq = (lane >> 4) << 3;
  int row0 = blockIdx.y * 128, col0 = blockIdx.x * 128;
  int sr = tid >> 3, sc = (tid & 7) * 8;

  f32x4 acc[4][4];
#pragma unroll
  for (int i = 0; i < 4; i++)
#pragma unroll
    for (int j = 0; j < 4; j++) acc[i][j] = (f32x4){0.f, 0.f, 0.f, 0.f};

  for (int k0 = 0; k0 < K; k0 += 64) {
    __syncthreads();  // previous iter's LDS readers done
#pragma unroll
    for (int ri = 0; ri < 4; ri++) {
      bf16x8 a_ld = *(const bf16x8*)&A[(size_t)(row0 + sr + ri * 32) * lda + k0 + sc];
      bf16x8 b_ld = *(const bf16x8*)&Bt[(size_t)(col0 + sr + ri * 32) * K + k0 + sc];
      *(bf16x8*)&As[(sr + ri * 32) * 72 + sc] = a_ld;
      *(bf16x8*)&Bs[(sr + ri * 32) * 72 + sc] = b_ld;
    }
    __syncthreads();
#pragma unroll
    for (int kk = 0; kk < 64; kk += 32) {
      bf16x8 af[4], bfr[4];
#pragma unroll
      for (int i = 0; i < 4; i++)
        af[i] = *(const bf16x8*)&As[(m0 + i * 16 + ml) * 72 + kk + kq];
#pragma unroll
      for (int j = 0; j < 4; j++)
        bfr[j] = *(const bf16x8*)&Bs[(n0 + j * 16 + ml) * 72 + kk + kq];
#pragma unroll
      for (int i = 0; i < 4; i++)
#pragma unroll
        for (int j = 0; j < 4; j++)
          acc[i][j] = __builtin_amdgcn_mfma_f32_16x16x32_bf16(af[i], bfr[j], acc[i][j], 0, 0, 0);
    }
  }
  // epilogue: C/D layout col=lane&15, row=(lane>>4)*4+reg
  int rbase = row0 + m0 + ((lane >> 4) << 2);
#pragma unroll
  for (int i = 0; i < 4; i++) {
#pragma unroll
    for (int j = 0; j < 4; j++) {
      int gc = col0 + n0 + j * 16 + ml;
#pragma unroll
      for (int r = 0; r < 4; r++) {
        int gr = rbase + i * 16 + r;
        float v = acc[i][j][r];
        size_t idx = (size_t)gr * ldc + gc;
        if (EPI == 0) {
          ((float*)C)[idx] = v;
        } else if (EPI == 1) {
          if (gc < silucut) v = v * sigm(v);
          ((u16*)C)[idx] = f2bf(v);
        } else if (EPI == 2) {
          ((float*)C)[idx] = g1f[idx] + v * g2f[idx];
        } else {
          ((float*)C)[idx] = f1[idx] + v;
        }
      }
    }
  }
}

// ---------- L2 normalize 64-wide slices of X1 (q|k halves), f32 in-place ----------
__global__ __launch_bounds__(256) void kl2norm(float* __restrict__ X1) {
  int lane = threadIdx.x & 63;
  size_t r64 = (size_t)blockIdx.x * 4 + (threadIdx.x >> 6);
  size_t t = r64 >> 4;
  int sl = (int)(r64 & 15);  // 0..7 = q slices, 8..15 = k slices
  size_t idx = t * 2048 + sl * 64 + lane;
  float vv = X1[idx];
  float s = vv * vv;
#pragma unroll
  for (int off = 32; off; off >>= 1) s += __shfl_xor(s, off);
  X1[idx] = vv / (sqrtf(s) + 1e-6f);
}

// ---------- headwise RMS norm: yat f32 -> yat bf16 (for Wo MFMA) ----------
__global__ __launch_bounds__(256) void kheadnorm(const float* __restrict__ y,
                                                 const float* __restrict__ hw,
                                                 u16* __restrict__ yo) {
  int lane = threadIdx.x & 63;
  size_t r = (size_t)blockIdx.x * 4 + (threadIdx.x >> 6);
  int h = (int)(r & 7);
  float vv = y[r * 64 + lane];
  float s = vv * vv;
#pragma unroll
  for (int off = 32; off; off >>= 1) s += __shfl_xor(s, off);
  yo[r * 64 + lane] = f2bf(vv * rsqrtf(s * (1.f / 64.f) + 1e-6f) * hw[h * 64 + lane]);
}

// ---------- LIF spike scan (f32; drive strided inside X1) ----------
__global__ __launch_bounds__(64) void klif(const float* __restrict__ dr, int drs,
                                           const float* __restrict__ ab,
                                           const float* __restrict__ bb,
                                           const float* __restrict__ asp,
                                           const float* __restrict__ bsp,
                                           float* __restrict__ alpha,
                                           float* __restrict__ beta) {
  int bh = blockIdx.x;
  int b = bh >> 3, h = bh & 7;
  int lane = threadIdx.x;
  float aspk = asp[h * 64 + lane];
  float bspk = bsp[h * 64 + lane];
  float mem = 0.f;
  for (int t0 = 0; t0 < TT; t0 += 16) {
    float drc[16], abc[16];
#pragma unroll
    for (int i = 0; i < 16; i++) {
      size_t rt = (size_t)(b * TT + t0 + i);
      drc[i] = dr[rt * drs + h * 64 + lane];
      abc[i] = ab[rt * HKk + h * 64 + lane];
    }
    float bbv = (lane < 16) ? bb[((size_t)(b * TT + t0 + lane)) * HH + h] : 0.f;
#pragma unroll
    for (int i = 0; i < 16; i++) {
      mem = 0.9f * mem + drc[i];
      float spike = (mem > 0.5f) ? 1.f : 0.f;
      mem -= 0.5f * spike;
      float r1 = spike, r2 = spike * bspk;
#pragma unroll
      for (int off = 32; off; off >>= 1) {
        r1 += __shfl_xor(r1, off);
        r2 += __shfl_xor(r2, off);
      }
      float bbi = __shfl(bbv, i);
      int active = (r1 > 0.f);
      float al = active ? sigm(abc[i] + aspk * spike) : 1.f;
      float bt = active ? sigm(bbi + r2) : 0.f;
      size_t rt = (size_t)(b * TT + t0 + i);
      alpha[rt * HKk + h * 64 + lane] = al;
      if (lane == 0) beta[rt * HH + h] = bt;
    }
  }
}

// ---------- gated delta-rule scan (f32; q/k/v strided inside X1) ----------
__global__ __launch_bounds__(64) void kscan(const float* __restrict__ X1, int xs,
                                            const float* __restrict__ alpha,
                                            const float* __restrict__ beta,
                                            float* __restrict__ y) {
  int bh = blockIdx.x;
  int b = bh >> 3, h = bh & 7;
  int lane = threadIdx.x;
  float S[64];
#pragma unroll
  for (int i = 0; i < 64; i++) S[i] = 0.f;
  __shared__ float2 sAK[8][64];
  __shared__ float2 sKQ[8][64];
  __shared__ float sv[8][64];
  __shared__ float sb[8];
  for (int t0 = 0; t0 < TT; t0 += 8) {
#pragma unroll
    for (int i = 0; i < 8; i++) {
      size_t rt = (size_t)(b * TT + t0 + i);
      size_t base = rt * xs + h * 64;
      float kv = X1[base + 512 + lane];
      sAK[i][lane] = make_float2(alpha[rt * HKk + h * 64 + lane], kv);
      sKQ[i][lane] = make_float2(kv, X1[base + lane]);
      sv[i][lane] = X1[base + 1024 + lane];
    }
    if (lane < 8) sb[lane] = beta[((size_t)(b * TT + t0 + lane)) * HH + h];
    __syncthreads();
#pragma unroll 1
    for (int i = 0; i < 8; i++) {
      float pr[4] = {0.f, 0.f, 0.f, 0.f};
#pragma unroll
      for (int kk = 0; kk < 64; kk++) {
        float2 ak = sAK[i][kk];
        S[kk] *= ak.x;
        pr[kk & 3] += ak.y * S[kk];
      }
      float pred = (pr[0] + pr[1]) + (pr[2] + pr[3]);
      float c = sb[i] * (sv[i][lane] - pred);
      float ou[4] = {0.f, 0.f, 0.f, 0.f};
#pragma unroll
      for (int kk = 0; kk < 64; kk++) {
        float2 kq = sKQ[i][kk];
        S[kk] += kq.x * c;
        ou[kk & 3] += kq.y * S[kk];
      }
      y[((size_t)(b * TT + t0 + i)) * HKk + h * 64 + lane] =
          (ou[0] + ou[1]) + (ou[2] + ou[3]);
    }
    __syncthreads();
  }
}

// ---------- SwiGLU combine in-place on bf16 f: f[:, :4096] *= f[:, 4096:] ----------
__global__ __launch_bounds__(256) void kmulg(u16* __restrict__ f) {
  size_t i = ((size_t)blockIdx.x * 256 + threadIdx.x) * 8;
  size_t r = i >> 12;
  int c = (int)(i & 4095);
  u16* p = f + r * 8192 + c;
#pragma unroll
  for (int j = 0; j < 8; j++) p[j] = f2bf(bf2f(p[j]) * bf2f(p[j + 4096]));
}

extern "C" void kernel_launch(void* const* d_in, const int* in_sizes, int n_in,
                              void* d_out, int out_size, void* d_ws, size_t ws_size,
                              hipStream_t stream) {
  const float *x = (const float*)d_in[0], *norm_in_w = (const float*)d_in[1],
              *conv_w = (const float*)d_in[2], *conv_b = (const float*)d_in[3],
              *Wq = (const float*)d_in[4], *Wk = (const float*)d_in[5],
              *Wv = (const float*)d_in[6], *Wo = (const float*)d_in[7],
              *Wspike = (const float*)d_in[8], *Wau = (const float*)d_in[9],
              *bau = (const float*)d_in[10], *Wad = (const float*)d_in[11],
              *bad_ = (const float*)d_in[12], *asp = (const float*)d_in[13],
              *Wbeta = (const float*)d_in[14], *bbeta = (const float*)d_in[15],
              *bsp = (const float*)d_in[16], *hnw = (const float*)d_in[17],
              *Wu1 = (const float*)d_in[18], *bu1 = (const float*)d_in[19],
              *Wu2 = (const float*)d_in[20], *bu2 = (const float*)d_in[21],
              *ffw = (const float*)d_in[22], *Wff1 = (const float*)d_in[23],
              *Wff3 = (const float*)d_in[24], *Wff2 = (const float*)d_in[25];
  (void)in_sizes; (void)n_in; (void)out_size; (void)ws_size;

  char* wsb = (char*)d_ws;
  size_t off = 0;
  auto alloc = [&](size_t bytes) {
    void* p = wsb + off;
    off += (bytes + 255) & ~(size_t)255;
    return p;
  };
  float* h    = (float*)alloc((size_t)BTt * DD * 4);       // 16 MiB
  u16*   hc   = (u16*)alloc((size_t)BTt * DD * 2);         // 8
  size_t qoff = off;  // overlay region start (dead before FFN)
  float* X1   = (float*)alloc((size_t)BTt * 2048 * 4);     // 32  q|k|v|drive
  float* ab   = (float*)alloc((size_t)BTt * HKk * 4);      // 8
  float* alph = (float*)alloc((size_t)BTt * HKk * 4);      // 8
  float* bb   = (float*)alloc((size_t)BTt * HH * 4);       // .125
  float* au   = (float*)alloc((size_t)BTt * 64 * 4);       // 1
  float* beta = (float*)alloc((size_t)BTt * HH * 4);       // .125
  float* u1   = (float*)alloc((size_t)BTt * 64 * 4);       // 1
  float* gate = (float*)alloc((size_t)BTt * DD * 4);       // 16
  float* yat  = (float*)alloc((size_t)BTt * HKk * 4);      // 8
  u16* yat_bf = (u16*)alloc((size_t)BTt * HKk * 2);        // 4  (overlay region = 78.25 MiB)
  // f_bf (64 MiB bf16 [4096,8192]) overlays [X1 .. gate-part] — all dead before FFN-up
  u16* f_bf   = (u16*)(wsb + qoff);
  float* y2   = (float*)alloc((size_t)BTt * DD * 4);       // 16
  u16* z_bf   = (u16*)alloc((size_t)BTt * DD * 2);         // 8
  u16* WtX    = (u16*)alloc((size_t)2048 * 1024 * 2);      // 4   [Wq|Wk|Wv|Wspike]^T
  u16* WtO    = (u16*)alloc((size_t)1024 * 512 * 2);       // 1
  u16* WtFF   = (u16*)alloc((size_t)8192 * 1024 * 2);      // 16  [Wff1|Wff3]^T
  u16* WtF2   = (u16*)alloc((size_t)1024 * 4096 * 2);      // 8   => total ~155 MiB

  // weight transposes (f32 -> bf16, Bt = [N,K] k-contiguous)
  ktrans<<<dim3(16, 32), 256, 0, stream>>>(Wq, WtX + (size_t)0 * 512 * 1024, 1024, 512);
  ktrans<<<dim3(16, 32), 256, 0, stream>>>(Wk, WtX + (size_t)1 * 512 * 1024, 1024, 512);
  ktrans<<<dim3(16, 32), 256, 0, stream>>>(Wv, WtX + (size_t)2 * 512 * 1024, 1024, 512);
  ktrans<<<dim3(16, 32), 256, 0, stream>>>(Wspike, WtX + (size_t)3 * 512 * 1024, 1024, 512);
  ktrans<<<dim3(32, 16), 256, 0, stream>>>(Wo, WtO, 512, 1024);
  ktrans<<<dim3(128, 32), 256, 0, stream>>>(Wff1, WtFF, 1024, 4096);
  ktrans<<<dim3(128, 32), 256, 0, stream>>>(Wff3, WtFF + (size_t)4096 * 1024, 1024, 4096);
  ktrans<<<dim3(32, 128), 256, 0, stream>>>(Wff2, WtF2, 4096, 1024);

  // front end
  krms<<<BTt, 256, 0, stream>>>(x, norm_in_w, h, 0);
  kconv<<<BTt * DD / 256, 256, 0, stream>>>(h, conv_w, conv_b, hc);

  // QKVD projection (MFMA): [4096,1024]bf16 @ [1024,2048] -> X1 f32 [4096,2048]
  kmfma<0><<<dim3(16, 32), 256, 0, stream>>>(
      hc, 1024, WtX, X1, 2048, BTt, 2048, 1024, nullptr, nullptr, nullptr, 0);

  // small projections (f32 compute)
  kgemm<<<dim3(1, 64), 256, 0, stream>>>(hc, 1, Wau, bau, au, BTt, 64, DD, 1);
  kgemm<<<dim3(8, 64), 256, 0, stream>>>(au, 0, Wad, bad_, ab, BTt, HKk, 64, 0);
  kgemm<<<dim3(1, 64), 256, 0, stream>>>(hc, 1, Wbeta, bbeta, bb, BTt, HH, DD, 0);

  kl2norm<<<BTt * 16 / 4, 256, 0, stream>>>(X1);
  klif<<<BB * HH, 64, 0, stream>>>(X1 + 1536, 2048, ab, bb, asp, bsp, alph, beta);
  kscan<<<BB * HH, 64, 0, stream>>>(X1, 2048, alph, beta, yat);
  kheadnorm<<<BTt * HH / 4, 256, 0, stream>>>(yat, hnw, yat_bf);

  // gate path (f32)
  kgemm<<<dim3(1, 64), 256, 0, stream>>>(x, 0, Wu1, bu1, u1, BTt, 64, DD, 1);
  kgemm<<<dim3(16, 64), 256, 0, stream>>>(u1, 0, Wu2, bu2, gate, BTt, DD, 64, 2);

  // y2 = x + (yat @ Wo) * gate   (MFMA, f32 out)
  kmfma<2><<<dim3(8, 32), 256, 0, stream>>>(
      yat_bf, 512, WtO, y2, 1024, BTt, 1024, 512, x, gate, nullptr, 0);

  // FFN (MFMA)
  krms<<<BTt, 256, 0, stream>>>(y2, ffw, z_bf, 1);
  kmfma<1><<<dim3(64, 32), 256, 0, stream>>>(
      z_bf, 1024, WtFF, f_bf, 8192, BTt, 8192, 1024, nullptr, nullptr, nullptr, 4096);
  kmulg<<<BTt * 4096 / 8 / 256, 256, 0, stream>>>(f_bf);
  kmfma<3><<<dim3(8, 32), 256, 0, stream>>>(
      f_bf, 8192, WtF2, d_out, 1024, BTt, 1024, 4096, nullptr, nullptr, y2, 0);
}

// Round 8
// 3344.563 us; speedup vs baseline: 2.8155x; 1.1768x over previous
//
#include <hip/hip_runtime.h>
#include <hip/hip_bf16.h>

#define BB 2
#define TT 2048
#define DD 1024
#define HH 8
#define HKk 512
#define BTt 4096  // BB*TT

typedef unsigned short u16;
typedef __attribute__((ext_vector_type(8))) short bf16x8;
typedef __attribute__((ext_vector_type(4))) float f32x4;

__device__ __forceinline__ u16 f2bf(float v) {
  union { float f; unsigned u; } c; c.f = v;
  return (u16)((c.u + 0x7fffu + ((c.u >> 16) & 1u)) >> 16);  // RNE
}
__device__ __forceinline__ float bf2f(u16 v) {
  union { unsigned u; float f; } c; c.u = ((unsigned)v) << 16; return c.f;
}
__device__ __forceinline__ float sigm(float x) { return 1.f / (1.f + expf(-x)); }

// ---------- weight transpose + cast: dst_bf16[n*K+k] = src_f32[k*N+n] ----------
__global__ __launch_bounds__(256) void ktrans(const float* __restrict__ src,
                                              u16* __restrict__ dst, int K, int N) {
  __shared__ u16 t[32][33];
  int n0 = blockIdx.x * 32, k0 = blockIdx.y * 32;
  int tx = threadIdx.x & 31, ty0 = threadIdx.x >> 5;
#pragma unroll
  for (int i = 0; i < 32; i += 8)
    t[ty0 + i][tx] = f2bf(src[(size_t)(k0 + ty0 + i) * N + n0 + tx]);
  __syncthreads();
#pragma unroll
  for (int i = 0; i < 32; i += 8)
    dst[(size_t)(n0 + ty0 + i) * K + k0 + tx] = t[tx][ty0 + i];
}

// ---------- RMS norm over 1024 cols (f32 in, f32 weights; obf: bf16 or f32 out) ----------
__global__ __launch_bounds__(256) void krms(const float* __restrict__ x,
                                            const float* __restrict__ w,
                                            void* __restrict__ out, int obf) {
  size_t row = blockIdx.x;
  __shared__ float red[4];
  float vals[4];
  float s = 0.f;
#pragma unroll
  for (int i = 0; i < 4; i++) {
    vals[i] = x[row * DD + threadIdx.x + i * 256];
    s += vals[i] * vals[i];
  }
#pragma unroll
  for (int off = 32; off; off >>= 1) s += __shfl_xor(s, off);
  if ((threadIdx.x & 63) == 0) red[threadIdx.x >> 6] = s;
  __syncthreads();
  float tot = red[0] + red[1] + red[2] + red[3];
  float sc = rsqrtf(tot * (1.f / DD) + 1e-6f);
#pragma unroll
  for (int i = 0; i < 4; i++) {
    size_t idx = row * DD + threadIdx.x + i * 256;
    float vv = vals[i] * sc * w[threadIdx.x + i * 256];
    if (obf) ((u16*)out)[idx] = f2bf(vv);
    else ((float*)out)[idx] = vv;
  }
}

// ---------- causal depthwise conv (KW=4) + bias + SiLU: f32 in -> bf16 out ----------
__global__ __launch_bounds__(256) void kconv(const float* __restrict__ hin,
                                             const float* __restrict__ cw,
                                             const float* __restrict__ cb,
                                             u16* __restrict__ hout) {
  size_t i = (size_t)blockIdx.x * 256 + threadIdx.x;
  int d = (int)(i & 1023);
  int bt = (int)(i >> 10);
  int b = bt >> 11, t = bt & 2047;
  float acc = cb[d];
#pragma unroll
  for (int j = 0; j < 4; j++) {
    int tt = t - 3 + j;
    if (tt >= 0) acc += hin[(((size_t)(b * TT + tt)) << 10) + d] * cw[d * 4 + j];
  }
  hout[i] = f2bf(acc * sigm(acc));
}

// ---------- small f32-compute GEMM: C_f32 = act(A@B + bias); A bf16 (abf=1) or f32 ----------
__global__ __launch_bounds__(256) void kgemm(const void* __restrict__ A, int abf,
                                             const float* __restrict__ Bm,
                                             const float* __restrict__ bias,
                                             float* __restrict__ C,
                                             int M, int N, int K, int act) {
  __shared__ __align__(16) float As[16][64];
  __shared__ __align__(16) float Bs[16][64];
  int tid = threadIdx.x;
  int tx = tid & 15, ty = tid >> 4;
  int row0 = blockIdx.y * 64, col0 = blockIdx.x * 64;
  float acc[4][4] = {};
  for (int k0 = 0; k0 < K; k0 += 16) {
#pragma unroll
    for (int l = 0; l < 4; l++) {
      int e = tid * 4 + l;
      int m = e >> 4, kk = e & 15;
      int gr = row0 + m;
      size_t ai = (size_t)gr * K + k0 + kk;
      As[kk][m] = (gr < M) ? (abf ? bf2f(((const u16*)A)[ai]) : ((const float*)A)[ai]) : 0.f;
    }
#pragma unroll
    for (int l = 0; l < 4; l++) {
      int e = tid + l * 256;
      int kk = e >> 6, n = e & 63;
      int gc = col0 + n;
      Bs[kk][n] = (gc < N) ? Bm[(size_t)(k0 + kk) * N + gc] : 0.f;
    }
    __syncthreads();
#pragma unroll
    for (int kk = 0; kk < 16; kk++) {
      float4 av = *(const float4*)&As[kk][ty * 4];
      float4 bv = *(const float4*)&Bs[kk][tx * 4];
      float a[4] = {av.x, av.y, av.z, av.w};
      float b[4] = {bv.x, bv.y, bv.z, bv.w};
#pragma unroll
      for (int i = 0; i < 4; i++)
#pragma unroll
        for (int j = 0; j < 4; j++) acc[i][j] += a[i] * b[j];
    }
    __syncthreads();
  }
#pragma unroll
  for (int i = 0; i < 4; i++) {
    int r = row0 + ty * 4 + i;
    if (r >= M) continue;
#pragma unroll
    for (int j = 0; j < 4; j++) {
      int cc = col0 + tx * 4 + j;
      if (cc >= N) continue;
      float vv = acc[i][j];
      if (bias) vv += bias[cc];
      if (act == 1) vv = vv * sigm(vv);
      else if (act == 2) vv = sigm(vv);
      C[(size_t)r * N + cc] = vv;
    }
  }
}

// ---------- big MFMA GEMM: C[M,N] = epi(A[M,K]bf16 @ Bt[N,K]bf16^T) ----------
// EPI 0: f32 store. 1: silu where col<silucut, bf16 store.
// 2: f32 store of g1f+acc*g2f. 3: f32 store of f1+acc.
template <int EPI>
__global__ __launch_bounds__(256) void kmfma(
    const u16* __restrict__ A, int lda, const u16* __restrict__ Bt,
    void* __restrict__ C, int ldc, int M, int N, int K,
    const float* __restrict__ g1f, const float* __restrict__ g2f,
    const float* __restrict__ f1, int silucut) {
  __shared__ __align__(16) u16 As[128 * 72];
  __shared__ __align__(16) u16 Bs[128 * 72];
  int tid = threadIdx.x;
  int lane = tid & 63, wv = tid >> 6;
  int m0 = (wv & 1) * 64, n0 = (wv >> 1) * 64;
  int ml = lane & 15, kq = (lane >> 4) << 3;
  int row0 = blockIdx.y * 128, col0 = blockIdx.x * 128;
  int sr = tid >> 3, sc = (tid & 7) * 8;

  f32x4 acc[4][4];
#pragma unroll
  for (int i = 0; i < 4; i++)
#pragma unroll
    for (int j = 0; j < 4; j++) acc[i][j] = (f32x4){0.f, 0.f, 0.f, 0.f};

  for (int k0 = 0; k0 < K; k0 += 64) {
    __syncthreads();  // previous iter's LDS readers done
#pragma unroll
    for (int ri = 0; ri < 4; ri++) {
      bf16x8 a_ld = *(const bf16x8*)&A[(size_t)(row0 + sr + ri * 32) * lda + k0 + sc];
      bf16x8 b_ld = *(const bf16x8*)&Bt[(size_t)(col0 + sr + ri * 32) * K + k0 + sc];
      *(bf16x8*)&As[(sr + ri * 32) * 72 + sc] = a_ld;
      *(bf16x8*)&Bs[(sr + ri * 32) * 72 + sc] = b_ld;
    }
    __syncthreads();
#pragma unroll
    for (int kk = 0; kk < 64; kk += 32) {
      bf16x8 af[4], bfr[4];
#pragma unroll
      for (int i = 0; i < 4; i++)
        af[i] = *(const bf16x8*)&As[(m0 + i * 16 + ml) * 72 + kk + kq];
#pragma unroll
      for (int j = 0; j < 4; j++)
        bfr[j] = *(const bf16x8*)&Bs[(n0 + j * 16 + ml) * 72 + kk + kq];
#pragma unroll
      for (int i = 0; i < 4; i++)
#pragma unroll
        for (int j = 0; j < 4; j++)
          acc[i][j] = __builtin_amdgcn_mfma_f32_16x16x32_bf16(af[i], bfr[j], acc[i][j], 0, 0, 0);
    }
  }
  // epilogue: C/D layout col=lane&15, row=(lane>>4)*4+reg
  int rbase = row0 + m0 + ((lane >> 4) << 2);
#pragma unroll
  for (int i = 0; i < 4; i++) {
#pragma unroll
    for (int j = 0; j < 4; j++) {
      int gc = col0 + n0 + j * 16 + ml;
#pragma unroll
      for (int r = 0; r < 4; r++) {
        int gr = rbase + i * 16 + r;
        float v = acc[i][j][r];
        size_t idx = (size_t)gr * ldc + gc;
        if (EPI == 0) {
          ((float*)C)[idx] = v;
        } else if (EPI == 1) {
          if (gc < silucut) v = v * sigm(v);
          ((u16*)C)[idx] = f2bf(v);
        } else if (EPI == 2) {
          ((float*)C)[idx] = g1f[idx] + v * g2f[idx];
        } else {
          ((float*)C)[idx] = f1[idx] + v;
        }
      }
    }
  }
}

// ---------- L2 normalize 64-wide slices of X1 (q|k halves), f32 in-place ----------
__global__ __launch_bounds__(256) void kl2norm(float* __restrict__ X1) {
  int lane = threadIdx.x & 63;
  size_t r64 = (size_t)blockIdx.x * 4 + (threadIdx.x >> 6);
  size_t t = r64 >> 4;
  int sl = (int)(r64 & 15);  // 0..7 = q slices, 8..15 = k slices
  size_t idx = t * 2048 + sl * 64 + lane;
  float vv = X1[idx];
  float s = vv * vv;
#pragma unroll
  for (int off = 32; off; off >>= 1) s += __shfl_xor(s, off);
  X1[idx] = vv / (sqrtf(s) + 1e-6f);
}

// ---------- headwise RMS norm: yat f32 -> yat bf16 (for Wo MFMA) ----------
__global__ __launch_bounds__(256) void kheadnorm(const float* __restrict__ y,
                                                 const float* __restrict__ hw,
                                                 u16* __restrict__ yo) {
  int lane = threadIdx.x & 63;
  size_t r = (size_t)blockIdx.x * 4 + (threadIdx.x >> 6);
  int h = (int)(r & 7);
  float vv = y[r * 64 + lane];
  float s = vv * vv;
#pragma unroll
  for (int off = 32; off; off >>= 1) s += __shfl_xor(s, off);
  yo[r * 64 + lane] = f2bf(vv * rsqrtf(s * (1.f / 64.f) + 1e-6f) * hw[h * 64 + lane]);
}

// ---------- LIF spike scan, batched reductions ----------
// FIX (r8): bbi = __shfl(bbv, i) must be executed by ALL lanes — in r6/r7 it
// sat inside `if (lane==0)`, and ds_bpermute from an EXEC-disabled source lane
// is undefined (read garbage beta_base -> 0.125 absmax). Round-5 semantics
// restored.
__global__ __launch_bounds__(64) void klif(const float* __restrict__ dr, int drs,
                                           const float* __restrict__ ab,
                                           const float* __restrict__ bb,
                                           const float* __restrict__ asp,
                                           const float* __restrict__ bsp,
                                           float* __restrict__ alpha,
                                           float* __restrict__ beta) {
  int bh = blockIdx.x;
  int b = bh >> 3, h = bh & 7;
  int lane = threadIdx.x;
  float aspk = asp[h * 64 + lane];
  float bspk = bsp[h * 64 + lane];
  float mem = 0.f;
  for (int t0 = 0; t0 < TT; t0 += 16) {
    float drc[16], abc[16], sp[16], r2[16];
    unsigned long long act[16];
#pragma unroll
    for (int i = 0; i < 16; i++) {
      size_t rt = (size_t)(b * TT + t0 + i);
      drc[i] = dr[rt * drs + h * 64 + lane];
      abc[i] = ab[rt * HKk + h * 64 + lane];
    }
    float bbv = (lane < 16) ? bb[((size_t)(b * TT + t0 + lane)) * HH + h] : 0.f;
    // phase 1: membrane recurrence (serial, VALU-only)
#pragma unroll
    for (int i = 0; i < 16; i++) {
      mem = 0.9f * mem + drc[i];
      sp[i] = (mem > 0.5f) ? 1.f : 0.f;
      mem -= 0.5f * sp[i];
    }
    // phase 2: 16 independent reductions, pipelined
#pragma unroll
    for (int i = 0; i < 16; i++) {
      act[i] = __ballot(sp[i] != 0.f);
      r2[i] = sp[i] * bspk;
    }
#pragma unroll
    for (int off = 32; off; off >>= 1)
#pragma unroll
      for (int i = 0; i < 16; i++) r2[i] += __shfl_xor(r2[i], off);
    // phase 3: gates
#pragma unroll
    for (int i = 0; i < 16; i++) {
      size_t rt = (size_t)(b * TT + t0 + i);
      int active = (act[i] != 0ull);
      float bbi = __shfl(bbv, i);  // all lanes participate (see FIX note)
      alpha[rt * HKk + h * 64 + lane] = active ? sigm(abc[i] + aspk * sp[i]) : 1.f;
      if (lane == 0) beta[rt * HH + h] = active ? sigm(bbi + r2[i]) : 0.f;
    }
  }
}

// ---------- gated delta-rule scan, v-split + k-split ----------
// 64 blocks = (b,h) x 4 v-groups, one wave each. lane = vv*4+kp.
// Each lane holds S[16] (k-rows kp*16..+15, one v-col). pred/out reduce over
// kp via 2 shfl_xor. Single wave per block -> barriers are cheap.
__global__ __launch_bounds__(64) void kscan(const float* __restrict__ X1, int xs,
                                            const float* __restrict__ alpha,
                                            const float* __restrict__ beta,
                                            float* __restrict__ y) {
  int bid = blockIdx.x;
  int bh = bid >> 2, vg = bid & 3;
  int b = bh >> 3, h = bh & 7;
  int lane = threadIdx.x;
  int vv = lane >> 2, kp = lane & 3;
  float S[16];
#pragma unroll
  for (int j = 0; j < 16; j++) S[j] = 0.f;
  __shared__ __align__(16) float sAl[8][64];
  __shared__ __align__(16) float sK[8][64];
  __shared__ __align__(16) float sQ[8][64];
  __shared__ float sV[8][16];
  __shared__ float sB[8];
  for (int t0 = 0; t0 < TT; t0 += 8) {
#pragma unroll
    for (int i = 0; i < 8; i++) {
      size_t rt = (size_t)(b * TT + t0 + i);
      size_t base = rt * xs + h * 64;
      sAl[i][lane] = alpha[rt * HKk + h * 64 + lane];
      sK[i][lane] = X1[base + 512 + lane];
      sQ[i][lane] = X1[base + lane];
      if (lane < 16) sV[i][lane] = X1[base + 1024 + vg * 16 + lane];
    }
    if (lane < 8) sB[lane] = beta[((size_t)(b * TT + t0 + lane)) * HH + h];
    __syncthreads();
#pragma unroll 1
    for (int i = 0; i < 8; i++) {
      float al[16], kv[16], qv[16];
#pragma unroll
      for (int j = 0; j < 4; j++) {
        *(float4*)&al[j * 4] = *(const float4*)&sAl[i][kp * 16 + j * 4];
        *(float4*)&kv[j * 4] = *(const float4*)&sK[i][kp * 16 + j * 4];
        *(float4*)&qv[j * 4] = *(const float4*)&sQ[i][kp * 16 + j * 4];
      }
      float vt = sV[i][vv];
      float bt = sB[i];
      float pr[4] = {0.f, 0.f, 0.f, 0.f};
#pragma unroll
      for (int j = 0; j < 16; j++) {
        S[j] *= al[j];
        pr[j & 3] += kv[j] * S[j];
      }
      float pp = (pr[0] + pr[1]) + (pr[2] + pr[3]);
      pp += __shfl_xor(pp, 1);
      pp += __shfl_xor(pp, 2);
      float c = bt * (vt - pp);
      float ou[4] = {0.f, 0.f, 0.f, 0.f};
#pragma unroll
      for (int j = 0; j < 16; j++) {
        S[j] += kv[j] * c;
        ou[j & 3] += qv[j] * S[j];
      }
      float op = (ou[0] + ou[1]) + (ou[2] + ou[3]);
      op += __shfl_xor(op, 1);
      op += __shfl_xor(op, 2);
      if (kp == 0)
        y[((size_t)(b * TT + t0 + i)) * HKk + h * 64 + vg * 16 + vv] = op;
    }
    __syncthreads();
  }
}

// ---------- SwiGLU combine in-place on bf16 f: f[:, :4096] *= f[:, 4096:] ----------
__global__ __launch_bounds__(256) void kmulg(u16* __restrict__ f) {
  size_t i = ((size_t)blockIdx.x * 256 + threadIdx.x) * 8;
  size_t r = i >> 12;
  int c = (int)(i & 4095);
  u16* p = f + r * 8192 + c;
#pragma unroll
  for (int j = 0; j < 8; j++) p[j] = f2bf(bf2f(p[j]) * bf2f(p[j + 4096]));
}

extern "C" void kernel_launch(void* const* d_in, const int* in_sizes, int n_in,
                              void* d_out, int out_size, void* d_ws, size_t ws_size,
                              hipStream_t stream) {
  const float *x = (const float*)d_in[0], *norm_in_w = (const float*)d_in[1],
              *conv_w = (const float*)d_in[2], *conv_b = (const float*)d_in[3],
              *Wq = (const float*)d_in[4], *Wk = (const float*)d_in[5],
              *Wv = (const float*)d_in[6], *Wo = (const float*)d_in[7],
              *Wspike = (const float*)d_in[8], *Wau = (const float*)d_in[9],
              *bau = (const float*)d_in[10], *Wad = (const float*)d_in[11],
              *bad_ = (const float*)d_in[12], *asp = (const float*)d_in[13],
              *Wbeta = (const float*)d_in[14], *bbeta = (const float*)d_in[15],
              *bsp = (const float*)d_in[16], *hnw = (const float*)d_in[17],
              *Wu1 = (const float*)d_in[18], *bu1 = (const float*)d_in[19],
              *Wu2 = (const float*)d_in[20], *bu2 = (const float*)d_in[21],
              *ffw = (const float*)d_in[22], *Wff1 = (const float*)d_in[23],
              *Wff3 = (const float*)d_in[24], *Wff2 = (const float*)d_in[25];
  (void)in_sizes; (void)n_in; (void)out_size; (void)ws_size;

  char* wsb = (char*)d_ws;
  size_t off = 0;
  auto alloc = [&](size_t bytes) {
    void* p = wsb + off;
    off += (bytes + 255) & ~(size_t)255;
    return p;
  };
  float* h    = (float*)alloc((size_t)BTt * DD * 4);       // 16 MiB
  u16*   hc   = (u16*)alloc((size_t)BTt * DD * 2);         // 8
  size_t qoff = off;  // overlay region start (dead before FFN)
  float* X1   = (float*)alloc((size_t)BTt * 2048 * 4);     // 32  q|k|v|drive
  float* ab   = (float*)alloc((size_t)BTt * HKk * 4);      // 8
  float* alph = (float*)alloc((size_t)BTt * HKk * 4);      // 8
  float* bb   = (float*)alloc((size_t)BTt * HH * 4);       // .125
  float* au   = (float*)alloc((size_t)BTt * 64 * 4);       // 1
  float* beta = (float*)alloc((size_t)BTt * HH * 4);       // .125
  float* u1   = (float*)alloc((size_t)BTt * 64 * 4);       // 1
  float* gate = (float*)alloc((size_t)BTt * DD * 4);       // 16
  float* yat  = (float*)alloc((size_t)BTt * HKk * 4);      // 8
  u16* yat_bf = (u16*)alloc((size_t)BTt * HKk * 2);        // 4  (overlay region = 78.25 MiB)
  // f_bf (64 MiB bf16 [4096,8192]) overlays [X1 .. gate-part] — all dead before FFN-up
  u16* f_bf   = (u16*)(wsb + qoff);
  float* y2   = (float*)alloc((size_t)BTt * DD * 4);       // 16
  u16* z_bf   = (u16*)alloc((size_t)BTt * DD * 2);         // 8
  u16* WtX    = (u16*)alloc((size_t)2048 * 1024 * 2);      // 4   [Wq|Wk|Wv|Wspike]^T
  u16* WtO    = (u16*)alloc((size_t)1024 * 512 * 2);       // 1
  u16* WtFF   = (u16*)alloc((size_t)8192 * 1024 * 2);      // 16  [Wff1|Wff3]^T
  u16* WtF2   = (u16*)alloc((size_t)1024 * 4096 * 2);      // 8   => total ~155 MiB

  // weight transposes (f32 -> bf16, Bt = [N,K] k-contiguous)
  ktrans<<<dim3(16, 32), 256, 0, stream>>>(Wq, WtX + (size_t)0 * 512 * 1024, 1024, 512);
  ktrans<<<dim3(16, 32), 256, 0, stream>>>(Wk, WtX + (size_t)1 * 512 * 1024, 1024, 512);
  ktrans<<<dim3(16, 32), 256, 0, stream>>>(Wv, WtX + (size_t)2 * 512 * 1024, 1024, 512);
  ktrans<<<dim3(16, 32), 256, 0, stream>>>(Wspike, WtX + (size_t)3 * 512 * 1024, 1024, 512);
  ktrans<<<dim3(32, 16), 256, 0, stream>>>(Wo, WtO, 512, 1024);
  ktrans<<<dim3(128, 32), 256, 0, stream>>>(Wff1, WtFF, 1024, 4096);
  ktrans<<<dim3(128, 32), 256, 0, stream>>>(Wff3, WtFF + (size_t)4096 * 1024, 1024, 4096);
  ktrans<<<dim3(32, 128), 256, 0, stream>>>(Wff2, WtF2, 4096, 1024);

  // front end
  krms<<<BTt, 256, 0, stream>>>(x, norm_in_w, h, 0);
  kconv<<<BTt * DD / 256, 256, 0, stream>>>(h, conv_w, conv_b, hc);

  // QKVD projection (MFMA): [4096,1024]bf16 @ [1024,2048] -> X1 f32 [4096,2048]
  kmfma<0><<<dim3(16, 32), 256, 0, stream>>>(
      hc, 1024, WtX, X1, 2048, BTt, 2048, 1024, nullptr, nullptr, nullptr, 0);

  // small projections (f32 compute)
  kgemm<<<dim3(1, 64), 256, 0, stream>>>(hc, 1, Wau, bau, au, BTt, 64, DD, 1);
  kgemm<<<dim3(8, 64), 256, 0, stream>>>(au, 0, Wad, bad_, ab, BTt, HKk, 64, 0);
  kgemm<<<dim3(1, 64), 256, 0, stream>>>(hc, 1, Wbeta, bbeta, bb, BTt, HH, DD, 0);

  kl2norm<<<BTt * 16 / 4, 256, 0, stream>>>(X1);
  klif<<<BB * HH, 64, 0, stream>>>(X1 + 1536, 2048, ab, bb, asp, bsp, alph, beta);
  kscan<<<BB * HH * 4, 64, 0, stream>>>(X1, 2048, alph, beta, yat);
  kheadnorm<<<BTt * HH / 4, 256, 0, stream>>>(yat, hnw, yat_bf);

  // gate path (f32)
  kgemm<<<dim3(1, 64), 256, 0, stream>>>(x, 0, Wu1, bu1, u1, BTt, 64, DD, 1);
  kgemm<<<dim3(16, 64), 256, 0, stream>>>(u1, 0, Wu2, bu2, gate, BTt, DD, 64, 2);

  // y2 = x + (yat @ Wo) * gate   (MFMA, f32 out)
  kmfma<2><<<dim3(8, 32), 256, 0, stream>>>(
      yat_bf, 512, WtO, y2, 1024, BTt, 1024, 512, x, gate, nullptr, 0);

  // FFN (MFMA)
  krms<<<BTt, 256, 0, stream>>>(y2, ffw, z_bf, 1);
  kmfma<1><<<dim3(64, 32), 256, 0, stream>>>(
      z_bf, 1024, WtFF, f_bf, 8192, BTt, 8192, 1024, nullptr, nullptr, nullptr, 4096);
  kmulg<<<BTt * 4096 / 8 / 256, 256, 0, stream>>>(f_bf);
  kmfma<3><<<dim3(8, 32), 256, 0, stream>>>(
      f_bf, 8192, WtF2, d_out, 1024, BTt, 1024, 4096, nullptr, nullptr, y2, 0);
}

// Round 9
// 1997.544 us; speedup vs baseline: 4.7142x; 1.6743x over previous
//
#include <hip/hip_runtime.h>
#include <hip/hip_bf16.h>

#define BB 2
#define TT 2048
#define DD 1024
#define HH 8
#define HKk 512
#define BTt 4096  // BB*TT
#define PREPSZ 2304  // floats per (bh,tile) prep block

typedef unsigned short u16;
typedef __attribute__((ext_vector_type(8))) short bf16x8;
typedef __attribute__((ext_vector_type(4))) float f32x4;

__device__ __forceinline__ u16 f2bf(float v) {
  union { float f; unsigned u; } c; c.f = v;
  return (u16)((c.u + 0x7fffu + ((c.u >> 16) & 1u)) >> 16);  // RNE
}
__device__ __forceinline__ float bf2f(u16 v) {
  union { unsigned u; float f; } c; c.u = ((unsigned)v) << 16; return c.f;
}
__device__ __forceinline__ float sigm(float x) { return 1.f / (1.f + expf(-x)); }

// ---------- weight transpose + cast: dst_bf16[n*K+k] = src_f32[k*N+n] ----------
__global__ __launch_bounds__(256) void ktrans(const float* __restrict__ src,
                                              u16* __restrict__ dst, int K, int N) {
  __shared__ u16 t[32][33];
  int n0 = blockIdx.x * 32, k0 = blockIdx.y * 32;
  int tx = threadIdx.x & 31, ty0 = threadIdx.x >> 5;
#pragma unroll
  for (int i = 0; i < 32; i += 8)
    t[ty0 + i][tx] = f2bf(src[(size_t)(k0 + ty0 + i) * N + n0 + tx]);
  __syncthreads();
#pragma unroll
  for (int i = 0; i < 32; i += 8)
    dst[(size_t)(n0 + ty0 + i) * K + k0 + tx] = t[tx][ty0 + i];
}

// ---------- RMS norm over 1024 cols ----------
__global__ __launch_bounds__(256) void krms(const float* __restrict__ x,
                                            const float* __restrict__ w,
                                            void* __restrict__ out, int obf) {
  size_t row = blockIdx.x;
  __shared__ float red[4];
  float vals[4];
  float s = 0.f;
#pragma unroll
  for (int i = 0; i < 4; i++) {
    vals[i] = x[row * DD + threadIdx.x + i * 256];
    s += vals[i] * vals[i];
  }
#pragma unroll
  for (int off = 32; off; off >>= 1) s += __shfl_xor(s, off);
  if ((threadIdx.x & 63) == 0) red[threadIdx.x >> 6] = s;
  __syncthreads();
  float tot = red[0] + red[1] + red[2] + red[3];
  float sc = rsqrtf(tot * (1.f / DD) + 1e-6f);
#pragma unroll
  for (int i = 0; i < 4; i++) {
    size_t idx = row * DD + threadIdx.x + i * 256;
    float vv = vals[i] * sc * w[threadIdx.x + i * 256];
    if (obf) ((u16*)out)[idx] = f2bf(vv);
    else ((float*)out)[idx] = vv;
  }
}

// ---------- causal depthwise conv (KW=4) + bias + SiLU: f32 -> bf16 ----------
__global__ __launch_bounds__(256) void kconv(const float* __restrict__ hin,
                                             const float* __restrict__ cw,
                                             const float* __restrict__ cb,
                                             u16* __restrict__ hout) {
  size_t i = (size_t)blockIdx.x * 256 + threadIdx.x;
  int d = (int)(i & 1023);
  int bt = (int)(i >> 10);
  int b = bt >> 11, t = bt & 2047;
  float acc = cb[d];
#pragma unroll
  for (int j = 0; j < 4; j++) {
    int tt = t - 3 + j;
    if (tt >= 0) acc += hin[(((size_t)(b * TT + tt)) << 10) + d] * cw[d * 4 + j];
  }
  hout[i] = f2bf(acc * sigm(acc));
}

// ---------- small f32-compute GEMM ----------
__global__ __launch_bounds__(256) void kgemm(const void* __restrict__ A, int abf,
                                             const float* __restrict__ Bm,
                                             const float* __restrict__ bias,
                                             float* __restrict__ C,
                                             int M, int N, int K, int act) {
  __shared__ __align__(16) float As[16][64];
  __shared__ __align__(16) float Bs[16][64];
  int tid = threadIdx.x;
  int tx = tid & 15, ty = tid >> 4;
  int row0 = blockIdx.y * 64, col0 = blockIdx.x * 64;
  float acc[4][4] = {};
  for (int k0 = 0; k0 < K; k0 += 16) {
#pragma unroll
    for (int l = 0; l < 4; l++) {
      int e = tid * 4 + l;
      int m = e >> 4, kk = e & 15;
      int gr = row0 + m;
      size_t ai = (size_t)gr * K + k0 + kk;
      As[kk][m] = (gr < M) ? (abf ? bf2f(((const u16*)A)[ai]) : ((const float*)A)[ai]) : 0.f;
    }
#pragma unroll
    for (int l = 0; l < 4; l++) {
      int e = tid + l * 256;
      int kk = e >> 6, n = e & 63;
      int gc = col0 + n;
      Bs[kk][n] = (gc < N) ? Bm[(size_t)(k0 + kk) * N + gc] : 0.f;
    }
    __syncthreads();
#pragma unroll
    for (int kk = 0; kk < 16; kk++) {
      float4 av = *(const float4*)&As[kk][ty * 4];
      float4 bv = *(const float4*)&Bs[kk][tx * 4];
      float a[4] = {av.x, av.y, av.z, av.w};
      float b[4] = {bv.x, bv.y, bv.z, bv.w};
#pragma unroll
      for (int i = 0; i < 4; i++)
#pragma unroll
        for (int j = 0; j < 4; j++) acc[i][j] += a[i] * b[j];
    }
    __syncthreads();
  }
#pragma unroll
  for (int i = 0; i < 4; i++) {
    int r = row0 + ty * 4 + i;
    if (r >= M) continue;
#pragma unroll
    for (int j = 0; j < 4; j++) {
      int cc = col0 + tx * 4 + j;
      if (cc >= N) continue;
      float vv = acc[i][j];
      if (bias) vv += bias[cc];
      if (act == 1) vv = vv * sigm(vv);
      else if (act == 2) vv = sigm(vv);
      C[(size_t)r * N + cc] = vv;
    }
  }
}

// ---------- big MFMA GEMM ----------
template <int EPI>
__global__ __launch_bounds__(256) void kmfma(
    const u16* __restrict__ A, int lda, const u16* __restrict__ Bt,
    void* __restrict__ C, int ldc, int M, int N, int K,
    const float* __restrict__ g1f, const float* __restrict__ g2f,
    const float* __restrict__ f1, int silucut) {
  __shared__ __align__(16) u16 As[128 * 72];
  __shared__ __align__(16) u16 Bs[128 * 72];
  int tid = threadIdx.x;
  int lane = tid & 63, wv = tid >> 6;
  int m0 = (wv & 1) * 64, n0 = (wv >> 1) * 64;
  int ml = lane & 15, kq = (lane >> 4) << 3;
  int row0 = blockIdx.y * 128, col0 = blockIdx.x * 128;
  int sr = tid >> 3, sc = (tid & 7) * 8;

  f32x4 acc[4][4];
#pragma unroll
  for (int i = 0; i < 4; i++)
#pragma unroll
    for (int j = 0; j < 4; j++) acc[i][j] = (f32x4){0.f, 0.f, 0.f, 0.f};

  for (int k0 = 0; k0 < K; k0 += 64) {
    __syncthreads();
#pragma unroll
    for (int ri = 0; ri < 4; ri++) {
      bf16x8 a_ld = *(const bf16x8*)&A[(size_t)(row0 + sr + ri * 32) * lda + k0 + sc];
      bf16x8 b_ld = *(const bf16x8*)&Bt[(size_t)(col0 + sr + ri * 32) * K + k0 + sc];
      *(bf16x8*)&As[(sr + ri * 32) * 72 + sc] = a_ld;
      *(bf16x8*)&Bs[(sr + ri * 32) * 72 + sc] = b_ld;
    }
    __syncthreads();
#pragma unroll
    for (int kk = 0; kk < 64; kk += 32) {
      bf16x8 af[4], bfr[4];
#pragma unroll
      for (int i = 0; i < 4; i++)
        af[i] = *(const bf16x8*)&As[(m0 + i * 16 + ml) * 72 + kk + kq];
#pragma unroll
      for (int j = 0; j < 4; j++)
        bfr[j] = *(const bf16x8*)&Bs[(n0 + j * 16 + ml) * 72 + kk + kq];
#pragma unroll
      for (int i = 0; i < 4; i++)
#pragma unroll
        for (int j = 0; j < 4; j++)
          acc[i][j] = __builtin_amdgcn_mfma_f32_16x16x32_bf16(af[i], bfr[j], acc[i][j], 0, 0, 0);
    }
  }
  int rbase = row0 + m0 + ((lane >> 4) << 2);
#pragma unroll
  for (int i = 0; i < 4; i++) {
#pragma unroll
    for (int j = 0; j < 4; j++) {
      int gc = col0 + n0 + j * 16 + ml;
#pragma unroll
      for (int r = 0; r < 4; r++) {
        int gr = rbase + i * 16 + r;
        float v = acc[i][j][r];
        size_t idx = (size_t)gr * ldc + gc;
        if (EPI == 0) {
          ((float*)C)[idx] = v;
        } else if (EPI == 1) {
          if (gc < silucut) v = v * sigm(v);
          ((u16*)C)[idx] = f2bf(v);
        } else if (EPI == 2) {
          ((float*)C)[idx] = g1f[idx] + v * g2f[idx];
        } else {
          ((float*)C)[idx] = f1[idx] + v;
        }
      }
    }
  }
}

// ---------- L2 normalize 64-wide slices of X1 (q|k halves) ----------
__global__ __launch_bounds__(256) void kl2norm(float* __restrict__ X1) {
  int lane = threadIdx.x & 63;
  size_t r64 = (size_t)blockIdx.x * 4 + (threadIdx.x >> 6);
  size_t t = r64 >> 4;
  int sl = (int)(r64 & 15);
  size_t idx = t * 2048 + sl * 64 + lane;
  float vv = X1[idx];
  float s = vv * vv;
#pragma unroll
  for (int off = 32; off; off >>= 1) s += __shfl_xor(s, off);
  X1[idx] = vv / (sqrtf(s) + 1e-6f);
}

// ---------- headwise RMS norm: yat f32 -> bf16 ----------
__global__ __launch_bounds__(256) void kheadnorm(const float* __restrict__ y,
                                                 const float* __restrict__ hw,
                                                 u16* __restrict__ yo) {
  int lane = threadIdx.x & 63;
  size_t r = (size_t)blockIdx.x * 4 + (threadIdx.x >> 6);
  int h = (int)(r & 7);
  float vv = y[r * 64 + lane];
  float s = vv * vv;
#pragma unroll
  for (int off = 32; off; off >>= 1) s += __shfl_xor(s, off);
  yo[r * 64 + lane] = f2bf(vv * rsqrtf(s * (1.f / 64.f) + 1e-6f) * hw[h * 64 + lane]);
}

// ---------- LIF spike scan (round-8 proven; all-lane shfl) ----------
__global__ __launch_bounds__(64) void klif(const float* __restrict__ dr, int drs,
                                           const float* __restrict__ ab,
                                           const float* __restrict__ bb,
                                           const float* __restrict__ asp,
                                           const float* __restrict__ bsp,
                                           float* __restrict__ alpha,
                                           float* __restrict__ beta) {
  int bh = blockIdx.x;
  int b = bh >> 3, h = bh & 7;
  int lane = threadIdx.x;
  float aspk = asp[h * 64 + lane];
  float bspk = bsp[h * 64 + lane];
  float mem = 0.f;
  for (int t0 = 0; t0 < TT; t0 += 16) {
    float drc[16], abc[16], sp[16], r2[16];
    unsigned long long act[16];
#pragma unroll
    for (int i = 0; i < 16; i++) {
      size_t rt = (size_t)(b * TT + t0 + i);
      drc[i] = dr[rt * drs + h * 64 + lane];
      abc[i] = ab[rt * HKk + h * 64 + lane];
    }
    float bbv = (lane < 16) ? bb[((size_t)(b * TT + t0 + lane)) * HH + h] : 0.f;
#pragma unroll
    for (int i = 0; i < 16; i++) {
      mem = 0.9f * mem + drc[i];
      sp[i] = (mem > 0.5f) ? 1.f : 0.f;
      mem -= 0.5f * sp[i];
    }
#pragma unroll
    for (int i = 0; i < 16; i++) {
      act[i] = __ballot(sp[i] != 0.f);
      r2[i] = sp[i] * bspk;
    }
#pragma unroll
    for (int off = 32; off; off >>= 1)
#pragma unroll
      for (int i = 0; i < 16; i++) r2[i] += __shfl_xor(r2[i], off);
#pragma unroll
    for (int i = 0; i < 16; i++) {
      size_t rt = (size_t)(b * TT + t0 + i);
      int active = (act[i] != 0ull);
      float bbi = __shfl(bbv, i);  // all lanes (EXEC-active) — r8 fix
      alpha[rt * HKk + h * 64 + lane] = active ? sigm(abc[i] + aspk * sp[i]) : 1.f;
      if (lane == 0) beta[rt * HH + h] = active ? sigm(bbi + r2[i]) : 0.f;
    }
  }
}

// ---------- kprep: chunk (C=8) UT-transform precompute, parallel over (bh,tile) ----------
// For S_t = (I - b_t k_t k_t^T) diag(a_t) S_{t-1} + b_t k_t v_t^T, with A_t = prefix
// prod of alpha: w = W8*(BV - K1*S0), out_t = Q1_t*S0 + GW*u, S' = A7.S0 + KH2*u.
// Block layout (floats): [K1 8x64 | Q1 8x64 | KH2 8x64 | BV 8x64 | A7 64 | GW 64 | pad]
__global__ __launch_bounds__(64) void kprep(const float* __restrict__ X1,
                                            const float* __restrict__ alph,
                                            const float* __restrict__ beta,
                                            float* __restrict__ prep) {
  int blk = blockIdx.x;
  int bh = blk >> 8, T = blk & 255;
  int b = bh >> 3, h = bh & 7;
  int lane = threadIdx.x;
  size_t row0 = (size_t)(b * TT) + (size_t)T * 8;
  float* out = prep + (size_t)blk * PREPSZ;
  __shared__ float sKP[8][64], sKiP[8][64], sQP[8][64];
  __shared__ float sBC[64], sG[64], sW[64], sBeta[8];

  // phase 1: lane = k
  float Pt[8], kv[8], kh[8];
  {
    float P = 1.f;
#pragma unroll
    for (int t = 0; t < 8; t++) {
      size_t rt = row0 + t;
      float a = alph[rt * HKk + h * 64 + lane];
      kv[t] = X1[rt * 2048 + h * 64 + 512 + lane];
      float qv = X1[rt * 2048 + h * 64 + lane];
      P *= a;
      Pt[t] = P;
      sQP[t][lane] = qv * P;
    }
    float P7 = Pt[7];
#pragma unroll
    for (int t = 0; t < 8; t++) {
      float KPv = kv[t] * Pt[t];
      float KiPv = kv[t] / Pt[t];
      sKP[t][lane] = KPv;
      sKiP[t][lane] = KiPv;
      kh[t] = P7 * KiPv;
      out[512 + t * 64 + lane] = sQP[t][lane];  // Q1
    }
    out[2048 + lane] = P7;  // A7
  }
  if (lane < 8) sBeta[lane] = beta[(row0 + lane) * HH + h];
  __syncthreads();
  // K1 = beta_t * k_t * A_t
#pragma unroll
  for (int t = 0; t < 8; t++) out[t * 64 + lane] = sBeta[t] * kv[t] * Pt[t];

  // phase 2: lane = (t2,s2): c_{ts} = KP_t . KiP_s ; g_{ts} = QP_t . KiP_s
  int t2 = lane >> 3, s2 = lane & 7;
  {
    float ac = 0.f, ag = 0.f;
#pragma unroll
    for (int k = 0; k < 64; k++) {
      float kip = sKiP[s2][k];
      ac += sKP[t2][k] * kip;
      ag += sQP[t2][k] * kip;
    }
    sBC[lane] = (t2 > s2) ? sBeta[t2] * ac : 0.f;
    sG[lane] = (t2 >= s2) ? ag : 0.f;
  }
  if (lane < 8) sW[lane * 8 + lane] = 1.f;
  __syncthreads();

  // phase 3a: W8 = (I + strictlower(BC))^{-1}, forward substitution (lanes r<t)
  for (int t = 1; t < 8; t++) {
    if (lane < t) {
      float a = -sBC[t * 8 + lane];
      for (int s = lane + 1; s < t; s++) a -= sBC[t * 8 + s] * sW[s * 8 + lane];
      sW[t * 8 + lane] = a;
    }
    __syncthreads();
  }
  // phase 3b: GW = G * W8 (lower)
  {
    float gw = 0.f;
    if (s2 <= t2)
      for (int s = s2; s <= t2; s++) gw += sG[t2 * 8 + s] * sW[s * 8 + s2];
    out[2112 + lane] = gw;
  }
  // phase 4: lane = k: KH2_r = sum_{s>=r} KH_s * W8[s][r]
#pragma unroll
  for (int r = 0; r < 8; r++) {
    float acc = 0.f;
    for (int s = r; s < 8; s++) acc += kh[s] * sW[s * 8 + r];
    out[1024 + r * 64 + lane] = acc;
  }
  // phase 5: lane = v: BV_t = beta_t * v_t
#pragma unroll
  for (int t = 0; t < 8; t++)
    out[1536 + t * 64 + lane] = sBeta[t] * X1[(row0 + t) * 2048 + h * 64 + 1024 + lane];
}

// ---------- kscan2: sequential chunk walker, 128 blocks = bh(16) x vg(8) ----------
// lane: kp = lane&7 (k-octant), vv = lane>>3 (v within group). S[8] per lane.
__global__ __launch_bounds__(64) void kscan2(const float* __restrict__ prep,
                                             float* __restrict__ y) {
  int bid = blockIdx.x;
  int bh = bid >> 3, vg = bid & 7;
  int b = bh >> 3, h = bh & 7;
  int lane = threadIdx.x;
  int kp = lane & 7, vv = lane >> 3;
  const float* gsrc = prep + (size_t)bh * 256 * PREPSZ;
  __shared__ __align__(16) float buf[2][PREPSZ];
  float S[8];
#pragma unroll
  for (int j = 0; j < 8; j++) S[j] = 0.f;

  float4 pf[9];
  const float* g0 = gsrc + (size_t)lane * 36;
#pragma unroll
  for (int i = 0; i < 9; i++) pf[i] = *(const float4*)(g0 + i * 4);
#pragma unroll
  for (int i = 0; i < 9; i++) *(float4*)&buf[0][lane * 36 + i * 4] = pf[i];
#pragma unroll
  for (int i = 0; i < 9; i++) pf[i] = *(const float4*)(g0 + PREPSZ + i * 4);
  __syncthreads();

  for (int T = 0; T < 256; T++) {
    const float* bp = buf[T & 1];
    // b_t = K1_t . S0 (partial over kp), qb_t = Q1_t . S0
    float bt[8], qb[8];
#pragma unroll
    for (int t = 0; t < 8; t++) {
      float4 k1a = *(const float4*)&bp[t * 64 + kp * 8];
      float4 k1b = *(const float4*)&bp[t * 64 + kp * 8 + 4];
      float4 q1a = *(const float4*)&bp[512 + t * 64 + kp * 8];
      float4 q1b = *(const float4*)&bp[512 + t * 64 + kp * 8 + 4];
      bt[t] = k1a.x * S[0] + k1a.y * S[1] + k1a.z * S[2] + k1a.w * S[3] +
              k1b.x * S[4] + k1b.y * S[5] + k1b.z * S[6] + k1b.w * S[7];
      qb[t] = q1a.x * S[0] + q1a.y * S[1] + q1a.z * S[2] + q1a.w * S[3] +
              q1b.x * S[4] + q1b.y * S[5] + q1b.z * S[6] + q1b.w * S[7];
    }
#pragma unroll
    for (int off = 1; off < 8; off <<= 1)
#pragma unroll
      for (int t = 0; t < 8; t++) {
        bt[t] += __shfl_xor(bt[t], off);
        qb[t] += __shfl_xor(qb[t], off);
      }
    // u = BV - b
    float u[8];
#pragma unroll
    for (int t = 0; t < 8; t++) u[t] = bp[1536 + t * 64 + vg * 8 + vv] - bt[t];
    // outs: out_t = qb_t + sum_{r<=t} GW[t][r] u_r
#pragma unroll
    for (int t = 0; t < 8; t++) {
      float o = qb[t];
#pragma unroll
      for (int r = 0; r < 8; r++)
        if (r <= t) o += bp[2112 + t * 8 + r] * u[r];
      if (kp == 0)
        y[((size_t)(b * TT) + (size_t)T * 8 + t) * HKk + h * 64 + vg * 8 + vv] = o;
    }
    // S update: S = A7 .* S + sum_r KH2_r * u_r
    {
      float4 a7a = *(const float4*)&bp[2048 + kp * 8];
      float4 a7b = *(const float4*)&bp[2048 + kp * 8 + 4];
      S[0] *= a7a.x; S[1] *= a7a.y; S[2] *= a7a.z; S[3] *= a7a.w;
      S[4] *= a7b.x; S[5] *= a7b.y; S[6] *= a7b.z; S[7] *= a7b.w;
#pragma unroll
      for (int r = 0; r < 8; r++) {
        float4 ha = *(const float4*)&bp[1024 + r * 64 + kp * 8];
        float4 hb = *(const float4*)&bp[1024 + r * 64 + kp * 8 + 4];
        float ur = u[r];
        S[0] += ha.x * ur; S[1] += ha.y * ur; S[2] += ha.z * ur; S[3] += ha.w * ur;
        S[4] += hb.x * ur; S[5] += hb.y * ur; S[6] += hb.z * ur; S[7] += hb.w * ur;
      }
    }
    // pipeline: stage tile T+1 (in pf) to LDS, prefetch tile T+2
    if (T < 255) {
      __syncthreads();
#pragma unroll
      for (int i = 0; i < 9; i++) *(float4*)&buf[(T + 1) & 1][lane * 36 + i * 4] = pf[i];
      if (T + 1 < 255) {
        const float* gn = g0 + (size_t)(T + 2) * PREPSZ;
#pragma unroll
        for (int i = 0; i < 9; i++) pf[i] = *(const float4*)(gn + i * 4);
      }
      __syncthreads();
    }
  }
}

// ---------- SwiGLU combine in-place on bf16 f ----------
__global__ __launch_bounds__(256) void kmulg(u16* __restrict__ f) {
  size_t i = ((size_t)blockIdx.x * 256 + threadIdx.x) * 8;
  size_t r = i >> 12;
  int c = (int)(i & 4095);
  u16* p = f + r * 8192 + c;
#pragma unroll
  for (int j = 0; j < 8; j++) p[j] = f2bf(bf2f(p[j]) * bf2f(p[j + 4096]));
}

extern "C" void kernel_launch(void* const* d_in, const int* in_sizes, int n_in,
                              void* d_out, int out_size, void* d_ws, size_t ws_size,
                              hipStream_t stream) {
  const float *x = (const float*)d_in[0], *norm_in_w = (const float*)d_in[1],
              *conv_w = (const float*)d_in[2], *conv_b = (const float*)d_in[3],
              *Wq = (const float*)d_in[4], *Wk = (const float*)d_in[5],
              *Wv = (const float*)d_in[6], *Wo = (const float*)d_in[7],
              *Wspike = (const float*)d_in[8], *Wau = (const float*)d_in[9],
              *bau = (const float*)d_in[10], *Wad = (const float*)d_in[11],
              *bad_ = (const float*)d_in[12], *asp = (const float*)d_in[13],
              *Wbeta = (const float*)d_in[14], *bbeta = (const float*)d_in[15],
              *bsp = (const float*)d_in[16], *hnw = (const float*)d_in[17],
              *Wu1 = (const float*)d_in[18], *bu1 = (const float*)d_in[19],
              *Wu2 = (const float*)d_in[20], *bu2 = (const float*)d_in[21],
              *ffw = (const float*)d_in[22], *Wff1 = (const float*)d_in[23],
              *Wff3 = (const float*)d_in[24], *Wff2 = (const float*)d_in[25];
  (void)in_sizes; (void)n_in; (void)out_size; (void)ws_size;

  char* wsb = (char*)d_ws;
  size_t off = 0;
  auto alloc = [&](size_t bytes) {
    void* p = wsb + off;
    off += (bytes + 255) & ~(size_t)255;
    return p;
  };
  float* h    = (float*)alloc((size_t)BTt * DD * 4);       // 16 MiB
  u16*   hc   = (u16*)alloc((size_t)BTt * DD * 2);         // 8
  size_t qoff = off;  // overlay region start (dead before FFN)
  float* X1   = (float*)alloc((size_t)BTt * 2048 * 4);     // 32  q|k|v|drive
  float* ab   = (float*)alloc((size_t)BTt * HKk * 4);      // 8
  float* alph = (float*)alloc((size_t)BTt * HKk * 4);      // 8
  float* bb   = (float*)alloc((size_t)BTt * HH * 4);       // .125
  float* au   = (float*)alloc((size_t)BTt * 64 * 4);       // 1
  float* beta = (float*)alloc((size_t)BTt * HH * 4);       // .125
  float* u1   = (float*)alloc((size_t)BTt * 64 * 4);       // 1
  float* gate = (float*)alloc((size_t)BTt * DD * 4);       // 16
  float* yat  = (float*)alloc((size_t)BTt * HKk * 4);      // 8
  u16* yat_bf = (u16*)alloc((size_t)BTt * HKk * 2);        // 4
  u16* f_bf   = (u16*)(wsb + qoff);  // 64 MiB overlay, dead-region reuse at FFN
  float* y2   = (float*)alloc((size_t)BTt * DD * 4);       // 16
  u16* z_bf   = (u16*)alloc((size_t)BTt * DD * 2);         // 8
  u16* WtX    = (u16*)alloc((size_t)2048 * 1024 * 2);      // 4
  u16* WtO    = (u16*)alloc((size_t)1024 * 512 * 2);       // 1
  u16* WtFF   = (u16*)alloc((size_t)8192 * 1024 * 2);      // 16
  u16* WtF2   = (u16*)alloc((size_t)1024 * 4096 * 2);      // 8
  float* prep = (float*)alloc((size_t)16 * 256 * PREPSZ * 4);  // 36 MiB => ~191 MiB total

  // weight transposes (f32 -> bf16, Bt = [N,K] k-contiguous)
  ktrans<<<dim3(16, 32), 256, 0, stream>>>(Wq, WtX + (size_t)0 * 512 * 1024, 1024, 512);
  ktrans<<<dim3(16, 32), 256, 0, stream>>>(Wk, WtX + (size_t)1 * 512 * 1024, 1024, 512);
  ktrans<<<dim3(16, 32), 256, 0, stream>>>(Wv, WtX + (size_t)2 * 512 * 1024, 1024, 512);
  ktrans<<<dim3(16, 32), 256, 0, stream>>>(Wspike, WtX + (size_t)3 * 512 * 1024, 1024, 512);
  ktrans<<<dim3(32, 16), 256, 0, stream>>>(Wo, WtO, 512, 1024);
  ktrans<<<dim3(128, 32), 256, 0, stream>>>(Wff1, WtFF, 1024, 4096);
  ktrans<<<dim3(128, 32), 256, 0, stream>>>(Wff3, WtFF + (size_t)4096 * 1024, 1024, 4096);
  ktrans<<<dim3(32, 128), 256, 0, stream>>>(Wff2, WtF2, 4096, 1024);

  // front end
  krms<<<BTt, 256, 0, stream>>>(x, norm_in_w, h, 0);
  kconv<<<BTt * DD / 256, 256, 0, stream>>>(h, conv_w, conv_b, hc);

  // QKVD projection (MFMA): -> X1 f32 [4096,2048]
  kmfma<0><<<dim3(16, 32), 256, 0, stream>>>(
      hc, 1024, WtX, X1, 2048, BTt, 2048, 1024, nullptr, nullptr, nullptr, 0);

  // small projections (f32 compute)
  kgemm<<<dim3(1, 64), 256, 0, stream>>>(hc, 1, Wau, bau, au, BTt, 64, DD, 1);
  kgemm<<<dim3(8, 64), 256, 0, stream>>>(au, 0, Wad, bad_, ab, BTt, HKk, 64, 0);
  kgemm<<<dim3(1, 64), 256, 0, stream>>>(hc, 1, Wbeta, bbeta, bb, BTt, HH, DD, 0);

  kl2norm<<<BTt * 16 / 4, 256, 0, stream>>>(X1);
  klif<<<BB * HH, 64, 0, stream>>>(X1 + 1536, 2048, ab, bb, asp, bsp, alph, beta);
  kprep<<<16 * 256, 64, 0, stream>>>(X1, alph, beta, prep);
  kscan2<<<16 * 8, 64, 0, stream>>>(prep, yat);
  kheadnorm<<<BTt * HH / 4, 256, 0, stream>>>(yat, hnw, yat_bf);

  // gate path (f32)
  kgemm<<<dim3(1, 64), 256, 0, stream>>>(x, 0, Wu1, bu1, u1, BTt, 64, DD, 1);
  kgemm<<<dim3(16, 64), 256, 0, stream>>>(u1, 0, Wu2, bu2, gate, BTt, DD, 64, 2);

  // y2 = x + (yat @ Wo) * gate   (MFMA, f32 out)
  kmfma<2><<<dim3(8, 32), 256, 0, stream>>>(
      yat_bf, 512, WtO, y2, 1024, BTt, 1024, 512, x, gate, nullptr, 0);

  // FFN (MFMA)
  krms<<<BTt, 256, 0, stream>>>(y2, ffw, z_bf, 1);
  kmfma<1><<<dim3(64, 32), 256, 0, stream>>>(
      z_bf, 1024, WtFF, f_bf, 8192, BTt, 8192, 1024, nullptr, nullptr, nullptr, 4096);
  kmulg<<<BTt * 4096 / 8 / 256, 256, 0, stream>>>(f_bf);
  kmfma<3><<<dim3(8, 32), 256, 0, stream>>>(
      f_bf, 8192, WtF2, d_out, 1024, BTt, 1024, 4096, nullptr, nullptr, y2, 0);
}

// Round 10
// 1557.593 us; speedup vs baseline: 6.0457x; 1.2825x over previous
//
#include <hip/hip_runtime.h>
#include <hip/hip_bf16.h>

#define BB 2
#define TT 2048
#define DD 1024
#define HH 8
#define HKk 512
#define BTt 4096  // BB*TT
#define PREPSZ 2304  // floats per (bh,tile) prep block

typedef unsigned short u16;
typedef __attribute__((ext_vector_type(8))) short bf16x8;
typedef __attribute__((ext_vector_type(4))) float f32x4;

__device__ __forceinline__ u16 f2bf(float v) {
  union { float f; unsigned u; } c; c.f = v;
  return (u16)((c.u + 0x7fffu + ((c.u >> 16) & 1u)) >> 16);  // RNE
}
__device__ __forceinline__ float bf2f(u16 v) {
  union { unsigned u; float f; } c; c.u = ((unsigned)v) << 16; return c.f;
}
__device__ __forceinline__ float sigm(float x) { return 1.f / (1.f + expf(-x)); }

// ---------- weight transpose + cast: dst_bf16[n*K+k] = src_f32[k*N+n] ----------
__global__ __launch_bounds__(256) void ktrans(const float* __restrict__ src,
                                              u16* __restrict__ dst, int K, int N) {
  __shared__ u16 t[32][33];
  int n0 = blockIdx.x * 32, k0 = blockIdx.y * 32;
  int tx = threadIdx.x & 31, ty0 = threadIdx.x >> 5;
#pragma unroll
  for (int i = 0; i < 32; i += 8)
    t[ty0 + i][tx] = f2bf(src[(size_t)(k0 + ty0 + i) * N + n0 + tx]);
  __syncthreads();
#pragma unroll
  for (int i = 0; i < 32; i += 8)
    dst[(size_t)(n0 + ty0 + i) * K + k0 + tx] = t[tx][ty0 + i];
}

// ---------- RMS norm over 1024 cols ----------
__global__ __launch_bounds__(256) void krms(const float* __restrict__ x,
                                            const float* __restrict__ w,
                                            void* __restrict__ out, int obf) {
  size_t row = blockIdx.x;
  __shared__ float red[4];
  float vals[4];
  float s = 0.f;
#pragma unroll
  for (int i = 0; i < 4; i++) {
    vals[i] = x[row * DD + threadIdx.x + i * 256];
    s += vals[i] * vals[i];
  }
#pragma unroll
  for (int off = 32; off; off >>= 1) s += __shfl_xor(s, off);
  if ((threadIdx.x & 63) == 0) red[threadIdx.x >> 6] = s;
  __syncthreads();
  float tot = red[0] + red[1] + red[2] + red[3];
  float sc = rsqrtf(tot * (1.f / DD) + 1e-6f);
#pragma unroll
  for (int i = 0; i < 4; i++) {
    size_t idx = row * DD + threadIdx.x + i * 256;
    float vv = vals[i] * sc * w[threadIdx.x + i * 256];
    if (obf) ((u16*)out)[idx] = f2bf(vv);
    else ((float*)out)[idx] = vv;
  }
}

// ---------- causal depthwise conv (KW=4) + bias + SiLU: f32 -> bf16 ----------
__global__ __launch_bounds__(256) void kconv(const float* __restrict__ hin,
                                             const float* __restrict__ cw,
                                             const float* __restrict__ cb,
                                             u16* __restrict__ hout) {
  size_t i = (size_t)blockIdx.x * 256 + threadIdx.x;
  int d = (int)(i & 1023);
  int bt = (int)(i >> 10);
  int b = bt >> 11, t = bt & 2047;
  float acc = cb[d];
#pragma unroll
  for (int j = 0; j < 4; j++) {
    int tt = t - 3 + j;
    if (tt >= 0) acc += hin[(((size_t)(b * TT + tt)) << 10) + d] * cw[d * 4 + j];
  }
  hout[i] = f2bf(acc * sigm(acc));
}

// ---------- small f32-compute GEMM ----------
__global__ __launch_bounds__(256) void kgemm(const void* __restrict__ A, int abf,
                                             const float* __restrict__ Bm,
                                             const float* __restrict__ bias,
                                             float* __restrict__ C,
                                             int M, int N, int K, int act) {
  __shared__ __align__(16) float As[16][64];
  __shared__ __align__(16) float Bs[16][64];
  int tid = threadIdx.x;
  int tx = tid & 15, ty = tid >> 4;
  int row0 = blockIdx.y * 64, col0 = blockIdx.x * 64;
  float acc[4][4] = {};
  for (int k0 = 0; k0 < K; k0 += 16) {
#pragma unroll
    for (int l = 0; l < 4; l++) {
      int e = tid * 4 + l;
      int m = e >> 4, kk = e & 15;
      int gr = row0 + m;
      size_t ai = (size_t)gr * K + k0 + kk;
      As[kk][m] = (gr < M) ? (abf ? bf2f(((const u16*)A)[ai]) : ((const float*)A)[ai]) : 0.f;
    }
#pragma unroll
    for (int l = 0; l < 4; l++) {
      int e = tid + l * 256;
      int kk = e >> 6, n = e & 63;
      int gc = col0 + n;
      Bs[kk][n] = (gc < N) ? Bm[(size_t)(k0 + kk) * N + gc] : 0.f;
    }
    __syncthreads();
#pragma unroll
    for (int kk = 0; kk < 16; kk++) {
      float4 av = *(const float4*)&As[kk][ty * 4];
      float4 bv = *(const float4*)&Bs[kk][tx * 4];
      float a[4] = {av.x, av.y, av.z, av.w};
      float b[4] = {bv.x, bv.y, bv.z, bv.w};
#pragma unroll
      for (int i = 0; i < 4; i++)
#pragma unroll
        for (int j = 0; j < 4; j++) acc[i][j] += a[i] * b[j];
    }
    __syncthreads();
  }
#pragma unroll
  for (int i = 0; i < 4; i++) {
    int r = row0 + ty * 4 + i;
    if (r >= M) continue;
#pragma unroll
    for (int j = 0; j < 4; j++) {
      int cc = col0 + tx * 4 + j;
      if (cc >= N) continue;
      float vv = acc[i][j];
      if (bias) vv += bias[cc];
      if (act == 1) vv = vv * sigm(vv);
      else if (act == 2) vv = sigm(vv);
      C[(size_t)r * N + cc] = vv;
    }
  }
}

// ---------- big MFMA GEMM ----------
template <int EPI>
__global__ __launch_bounds__(256) void kmfma(
    const u16* __restrict__ A, int lda, const u16* __restrict__ Bt,
    void* __restrict__ C, int ldc, int M, int N, int K,
    const float* __restrict__ g1f, const float* __restrict__ g2f,
    const float* __restrict__ f1, int silucut) {
  __shared__ __align__(16) u16 As[128 * 72];
  __shared__ __align__(16) u16 Bs[128 * 72];
  int tid = threadIdx.x;
  int lane = tid & 63, wv = tid >> 6;
  int m0 = (wv & 1) * 64, n0 = (wv >> 1) * 64;
  int ml = lane & 15, kq = (lane >> 4) << 3;
  int row0 = blockIdx.y * 128, col0 = blockIdx.x * 128;
  int sr = tid >> 3, sc = (tid & 7) * 8;

  f32x4 acc[4][4];
#pragma unroll
  for (int i = 0; i < 4; i++)
#pragma unroll
    for (int j = 0; j < 4; j++) acc[i][j] = (f32x4){0.f, 0.f, 0.f, 0.f};

  for (int k0 = 0; k0 < K; k0 += 64) {
    __syncthreads();
#pragma unroll
    for (int ri = 0; ri < 4; ri++) {
      bf16x8 a_ld = *(const bf16x8*)&A[(size_t)(row0 + sr + ri * 32) * lda + k0 + sc];
      bf16x8 b_ld = *(const bf16x8*)&Bt[(size_t)(col0 + sr + ri * 32) * K + k0 + sc];
      *(bf16x8*)&As[(sr + ri * 32) * 72 + sc] = a_ld;
      *(bf16x8*)&Bs[(sr + ri * 32) * 72 + sc] = b_ld;
    }
    __syncthreads();
#pragma unroll
    for (int kk = 0; kk < 64; kk += 32) {
      bf16x8 af[4], bfr[4];
#pragma unroll
      for (int i = 0; i < 4; i++)
        af[i] = *(const bf16x8*)&As[(m0 + i * 16 + ml) * 72 + kk + kq];
#pragma unroll
      for (int j = 0; j < 4; j++)
        bfr[j] = *(const bf16x8*)&Bs[(n0 + j * 16 + ml) * 72 + kk + kq];
#pragma unroll
      for (int i = 0; i < 4; i++)
#pragma unroll
        for (int j = 0; j < 4; j++)
          acc[i][j] = __builtin_amdgcn_mfma_f32_16x16x32_bf16(af[i], bfr[j], acc[i][j], 0, 0, 0);
    }
  }
  int rbase = row0 + m0 + ((lane >> 4) << 2);
#pragma unroll
  for (int i = 0; i < 4; i++) {
#pragma unroll
    for (int j = 0; j < 4; j++) {
      int gc = col0 + n0 + j * 16 + ml;
#pragma unroll
      for (int r = 0; r < 4; r++) {
        int gr = rbase + i * 16 + r;
        float v = acc[i][j][r];
        size_t idx = (size_t)gr * ldc + gc;
        if (EPI == 0) {
          ((float*)C)[idx] = v;
        } else if (EPI == 1) {
          if (gc < silucut) v = v * sigm(v);
          ((u16*)C)[idx] = f2bf(v);
        } else if (EPI == 2) {
          ((float*)C)[idx] = g1f[idx] + v * g2f[idx];
        } else {
          ((float*)C)[idx] = f1[idx] + v;
        }
      }
    }
  }
}

// ---------- L2 normalize 64-wide slices of X1 (q|k halves) ----------
__global__ __launch_bounds__(256) void kl2norm(float* __restrict__ X1) {
  int lane = threadIdx.x & 63;
  size_t r64 = (size_t)blockIdx.x * 4 + (threadIdx.x >> 6);
  size_t t = r64 >> 4;
  int sl = (int)(r64 & 15);
  size_t idx = t * 2048 + sl * 64 + lane;
  float vv = X1[idx];
  float s = vv * vv;
#pragma unroll
  for (int off = 32; off; off >>= 1) s += __shfl_xor(s, off);
  X1[idx] = vv / (sqrtf(s) + 1e-6f);
}

// ---------- headwise RMS norm: yat f32 -> bf16 ----------
__global__ __launch_bounds__(256) void kheadnorm(const float* __restrict__ y,
                                                 const float* __restrict__ hw,
                                                 u16* __restrict__ yo) {
  int lane = threadIdx.x & 63;
  size_t r = (size_t)blockIdx.x * 4 + (threadIdx.x >> 6);
  int h = (int)(r & 7);
  float vv = y[r * 64 + lane];
  float s = vv * vv;
#pragma unroll
  for (int off = 32; off; off >>= 1) s += __shfl_xor(s, off);
  yo[r * 64 + lane] = f2bf(vv * rsqrtf(s * (1.f / 64.f) + 1e-6f) * hw[h * 64 + lane]);
}

// ---------- klifA: membrane recurrence only -> packed spike bitmasks ----------
// 16 blocks (b,h) x 64 lanes (k). Serial over T with double-buffered 32-step
// tiles: loads are independent of the FMA chain and prefetched a tile ahead
// (r9's klif was load-serialized at 48 VGPRs -> 10.5k cyc/tile).
// masks[bh][w][lane] bit i = spike at t = w*32+i.
__global__ __launch_bounds__(64) void klifA(const float* __restrict__ dr, int drs,
                                            unsigned* __restrict__ masks) {
  int bh = blockIdx.x;
  int b = bh >> 3, h = bh & 7;
  int lane = threadIdx.x;
  float cur[32], nxt[32];
#pragma unroll
  for (int i = 0; i < 32; i++)
    cur[i] = dr[(size_t)(b * TT + i) * drs + h * 64 + lane];
  float mem = 0.f;
  for (int t0 = 0; t0 < TT; t0 += 32) {
    if (t0 + 32 < TT) {
#pragma unroll
      for (int i = 0; i < 32; i++)
        nxt[i] = dr[(size_t)(b * TT + t0 + 32 + i) * drs + h * 64 + lane];
    }
    unsigned m = 0;
#pragma unroll
    for (int i = 0; i < 32; i++) {
      mem = 0.9f * mem + cur[i];
      int s = (mem > 0.5f) ? 1 : 0;
      mem -= s ? 0.5f : 0.f;
      m |= ((unsigned)s) << i;
    }
    masks[((size_t)bh * 64 + (t0 >> 5)) * 64 + lane] = m;
#pragma unroll
    for (int i = 0; i < 32; i++) cur[i] = nxt[i];
  }
}

// ---------- klifB: gates from spike masks, fully parallel over (bh, t-chunk) ----------
// 256 blocks = bh(16) x tc(16); each handles 128 timesteps; lane = k.
__global__ __launch_bounds__(64) void klifB(const unsigned* __restrict__ masks,
                                            const float* __restrict__ ab,
                                            const float* __restrict__ bb,
                                            const float* __restrict__ asp,
                                            const float* __restrict__ bsp,
                                            float* __restrict__ alpha,
                                            float* __restrict__ beta) {
  int blk = blockIdx.x;
  int bh = blk >> 4, tc = blk & 15;
  int b = bh >> 3, h = bh & 7;
  int lane = threadIdx.x;
  float aspk = asp[h * 64 + lane];
  float bspk = bsp[h * 64 + lane];
#pragma unroll
  for (int g = 0; g < 2; g++) {
    size_t row0 = (size_t)(b * TT) + tc * 128 + g * 64;
    unsigned m0 = masks[((size_t)bh * 64 + (tc * 4 + g * 2 + 0)) * 64 + lane];
    unsigned m1 = masks[((size_t)bh * 64 + (tc * 4 + g * 2 + 1)) * 64 + lane];
    float bbv = bb[(row0 + lane) * HH + h];
#pragma unroll
    for (int tt = 0; tt < 64; tt++) {
      unsigned mw = (tt < 32) ? m0 : m1;
      int s = (mw >> (tt & 31)) & 1;
      unsigned long long act = __ballot(s != 0);
      float sp = (float)s;
      float r2 = sp * bspk;
#pragma unroll
      for (int off = 32; off; off >>= 1) r2 += __shfl_xor(r2, off);
      float bbi = __shfl(bbv, tt);  // all lanes EXEC-active (r8 lesson)
      size_t rt = row0 + tt;
      float abv = ab[rt * HKk + h * 64 + lane];
      int active = (act != 0ull);
      alpha[rt * HKk + h * 64 + lane] = active ? sigm(abv + aspk * sp) : 1.f;
      if (lane == 0) beta[rt * HH + h] = active ? sigm(bbi + r2) : 0.f;
    }
  }
}

// ---------- kprep: chunk (C=8) UT-transform precompute (r9 proven) ----------
__global__ __launch_bounds__(64) void kprep(const float* __restrict__ X1,
                                            const float* __restrict__ alph,
                                            const float* __restrict__ beta,
                                            float* __restrict__ prep) {
  int blk = blockIdx.x;
  int bh = blk >> 8, T = blk & 255;
  int b = bh >> 3, h = bh & 7;
  int lane = threadIdx.x;
  size_t row0 = (size_t)(b * TT) + (size_t)T * 8;
  float* out = prep + (size_t)blk * PREPSZ;
  __shared__ float sKP[8][64], sKiP[8][64], sQP[8][64];
  __shared__ float sBC[64], sG[64], sW[64], sBeta[8];

  float Pt[8], kv[8], kh[8];
  {
    float P = 1.f;
#pragma unroll
    for (int t = 0; t < 8; t++) {
      size_t rt = row0 + t;
      float a = alph[rt * HKk + h * 64 + lane];
      kv[t] = X1[rt * 2048 + h * 64 + 512 + lane];
      float qv = X1[rt * 2048 + h * 64 + lane];
      P *= a;
      Pt[t] = P;
      sQP[t][lane] = qv * P;
    }
    float P7 = Pt[7];
#pragma unroll
    for (int t = 0; t < 8; t++) {
      float KPv = kv[t] * Pt[t];
      float KiPv = kv[t] / Pt[t];
      sKP[t][lane] = KPv;
      sKiP[t][lane] = KiPv;
      kh[t] = P7 * KiPv;
      out[512 + t * 64 + lane] = sQP[t][lane];  // Q1
    }
    out[2048 + lane] = P7;  // A7
  }
  if (lane < 8) sBeta[lane] = beta[(row0 + lane) * HH + h];
  __syncthreads();
#pragma unroll
  for (int t = 0; t < 8; t++) out[t * 64 + lane] = sBeta[t] * kv[t] * Pt[t];

  int t2 = lane >> 3, s2 = lane & 7;
  {
    float ac = 0.f, ag = 0.f;
#pragma unroll
    for (int k = 0; k < 64; k++) {
      float kip = sKiP[s2][k];
      ac += sKP[t2][k] * kip;
      ag += sQP[t2][k] * kip;
    }
    sBC[lane] = (t2 > s2) ? sBeta[t2] * ac : 0.f;
    sG[lane] = (t2 >= s2) ? ag : 0.f;
  }
  if (lane < 8) sW[lane * 8 + lane] = 1.f;
  __syncthreads();

  for (int t = 1; t < 8; t++) {
    if (lane < t) {
      float a = -sBC[t * 8 + lane];
      for (int s = lane + 1; s < t; s++) a -= sBC[t * 8 + s] * sW[s * 8 + lane];
      sW[t * 8 + lane] = a;
    }
    __syncthreads();
  }
  {
    float gw = 0.f;
    if (s2 <= t2)
      for (int s = s2; s <= t2; s++) gw += sG[t2 * 8 + s] * sW[s * 8 + s2];
    out[2112 + lane] = gw;
  }
#pragma unroll
  for (int r = 0; r < 8; r++) {
    float acc = 0.f;
    for (int s = r; s < 8; s++) acc += kh[s] * sW[s * 8 + r];
    out[1024 + r * 64 + lane] = acc;
  }
#pragma unroll
  for (int t = 0; t < 8; t++)
    out[1536 + t * 64 + lane] = sBeta[t] * X1[(row0 + t) * 2048 + h * 64 + 1024 + lane];
}

// ---------- kscan2: sequential chunk walker (r9 proven) ----------
__global__ __launch_bounds__(64) void kscan2(const float* __restrict__ prep,
                                             float* __restrict__ y) {
  int bid = blockIdx.x;
  int bh = bid >> 3, vg = bid & 7;
  int b = bh >> 3, h = bh & 7;
  int lane = threadIdx.x;
  int kp = lane & 7, vv = lane >> 3;
  const float* gsrc = prep + (size_t)bh * 256 * PREPSZ;
  __shared__ __align__(16) float buf[2][PREPSZ];
  float S[8];
#pragma unroll
  for (int j = 0; j < 8; j++) S[j] = 0.f;

  float4 pf[9];
  const float* g0 = gsrc + (size_t)lane * 36;
#pragma unroll
  for (int i = 0; i < 9; i++) pf[i] = *(const float4*)(g0 + i * 4);
#pragma unroll
  for (int i = 0; i < 9; i++) *(float4*)&buf[0][lane * 36 + i * 4] = pf[i];
#pragma unroll
  for (int i = 0; i < 9; i++) pf[i] = *(const float4*)(g0 + PREPSZ + i * 4);
  __syncthreads();

  for (int T = 0; T < 256; T++) {
    const float* bp = buf[T & 1];
    float bt[8], qb[8];
#pragma unroll
    for (int t = 0; t < 8; t++) {
      float4 k1a = *(const float4*)&bp[t * 64 + kp * 8];
      float4 k1b = *(const float4*)&bp[t * 64 + kp * 8 + 4];
      float4 q1a = *(const float4*)&bp[512 + t * 64 + kp * 8];
      float4 q1b = *(const float4*)&bp[512 + t * 64 + kp * 8 + 4];
      bt[t] = k1a.x * S[0] + k1a.y * S[1] + k1a.z * S[2] + k1a.w * S[3] +
              k1b.x * S[4] + k1b.y * S[5] + k1b.z * S[6] + k1b.w * S[7];
      qb[t] = q1a.x * S[0] + q1a.y * S[1] + q1a.z * S[2] + q1a.w * S[3] +
              q1b.x * S[4] + q1b.y * S[5] + q1b.z * S[6] + q1b.w * S[7];
    }
#pragma unroll
    for (int off = 1; off < 8; off <<= 1)
#pragma unroll
      for (int t = 0; t < 8; t++) {
        bt[t] += __shfl_xor(bt[t], off);
        qb[t] += __shfl_xor(qb[t], off);
      }
    float u[8];
#pragma unroll
    for (int t = 0; t < 8; t++) u[t] = bp[1536 + t * 64 + vg * 8 + vv] - bt[t];
#pragma unroll
    for (int t = 0; t < 8; t++) {
      float o = qb[t];
#pragma unroll
      for (int r = 0; r < 8; r++)
        if (r <= t) o += bp[2112 + t * 8 + r] * u[r];
      if (kp == 0)
        y[((size_t)(b * TT) + (size_t)T * 8 + t) * HKk + h * 64 + vg * 8 + vv] = o;
    }
    {
      float4 a7a = *(const float4*)&bp[2048 + kp * 8];
      float4 a7b = *(const float4*)&bp[2048 + kp * 8 + 4];
      S[0] *= a7a.x; S[1] *= a7a.y; S[2] *= a7a.z; S[3] *= a7a.w;
      S[4] *= a7b.x; S[5] *= a7b.y; S[6] *= a7b.z; S[7] *= a7b.w;
#pragma unroll
      for (int r = 0; r < 8; r++) {
        float4 ha = *(const float4*)&bp[1024 + r * 64 + kp * 8];
        float4 hb = *(const float4*)&bp[1024 + r * 64 + kp * 8 + 4];
        float ur = u[r];
        S[0] += ha.x * ur; S[1] += ha.y * ur; S[2] += ha.z * ur; S[3] += ha.w * ur;
        S[4] += hb.x * ur; S[5] += hb.y * ur; S[6] += hb.z * ur; S[7] += hb.w * ur;
      }
    }
    if (T < 255) {
      __syncthreads();
#pragma unroll
      for (int i = 0; i < 9; i++) *(float4*)&buf[(T + 1) & 1][lane * 36 + i * 4] = pf[i];
      if (T + 1 < 255) {
        const float* gn = g0 + (size_t)(T + 2) * PREPSZ;
#pragma unroll
        for (int i = 0; i < 9; i++) pf[i] = *(const float4*)(gn + i * 4);
      }
      __syncthreads();
    }
  }
}

// ---------- SwiGLU combine in-place on bf16 f ----------
__global__ __launch_bounds__(256) void kmulg(u16* __restrict__ f) {
  size_t i = ((size_t)blockIdx.x * 256 + threadIdx.x) * 8;
  size_t r = i >> 12;
  int c = (int)(i & 4095);
  u16* p = f + r * 8192 + c;
#pragma unroll
  for (int j = 0; j < 8; j++) p[j] = f2bf(bf2f(p[j]) * bf2f(p[j + 4096]));
}

extern "C" void kernel_launch(void* const* d_in, const int* in_sizes, int n_in,
                              void* d_out, int out_size, void* d_ws, size_t ws_size,
                              hipStream_t stream) {
  const float *x = (const float*)d_in[0], *norm_in_w = (const float*)d_in[1],
              *conv_w = (const float*)d_in[2], *conv_b = (const float*)d_in[3],
              *Wq = (const float*)d_in[4], *Wk = (const float*)d_in[5],
              *Wv = (const float*)d_in[6], *Wo = (const float*)d_in[7],
              *Wspike = (const float*)d_in[8], *Wau = (const float*)d_in[9],
              *bau = (const float*)d_in[10], *Wad = (const float*)d_in[11],
              *bad_ = (const float*)d_in[12], *asp = (const float*)d_in[13],
              *Wbeta = (const float*)d_in[14], *bbeta = (const float*)d_in[15],
              *bsp = (const float*)d_in[16], *hnw = (const float*)d_in[17],
              *Wu1 = (const float*)d_in[18], *bu1 = (const float*)d_in[19],
              *Wu2 = (const float*)d_in[20], *bu2 = (const float*)d_in[21],
              *ffw = (const float*)d_in[22], *Wff1 = (const float*)d_in[23],
              *Wff3 = (const float*)d_in[24], *Wff2 = (const float*)d_in[25];
  (void)in_sizes; (void)n_in; (void)out_size; (void)ws_size;

  char* wsb = (char*)d_ws;
  size_t off = 0;
  auto alloc = [&](size_t bytes) {
    void* p = wsb + off;
    off += (bytes + 255) & ~(size_t)255;
    return p;
  };
  float* h    = (float*)alloc((size_t)BTt * DD * 4);       // 16 MiB
  u16*   hc   = (u16*)alloc((size_t)BTt * DD * 2);         // 8
  size_t qoff = off;  // overlay region start (dead before FFN)
  float* X1   = (float*)alloc((size_t)BTt * 2048 * 4);     // 32  q|k|v|drive
  float* ab   = (float*)alloc((size_t)BTt * HKk * 4);      // 8
  float* alph = (float*)alloc((size_t)BTt * HKk * 4);      // 8
  float* bb   = (float*)alloc((size_t)BTt * HH * 4);       // .125
  float* au   = (float*)alloc((size_t)BTt * 64 * 4);       // 1
  float* beta = (float*)alloc((size_t)BTt * HH * 4);       // .125
  float* u1   = (float*)alloc((size_t)BTt * 64 * 4);       // 1
  float* gate = (float*)alloc((size_t)BTt * DD * 4);       // 16
  float* yat  = (float*)alloc((size_t)BTt * HKk * 4);      // 8
  u16* yat_bf = (u16*)alloc((size_t)BTt * HKk * 2);        // 4
  u16* f_bf   = (u16*)(wsb + qoff);  // 64 MiB overlay, dead-region reuse at FFN
  float* y2   = (float*)alloc((size_t)BTt * DD * 4);       // 16
  u16* z_bf   = (u16*)alloc((size_t)BTt * DD * 2);         // 8
  u16* WtX    = (u16*)alloc((size_t)2048 * 1024 * 2);      // 4
  u16* WtO    = (u16*)alloc((size_t)1024 * 512 * 2);       // 1
  u16* WtFF   = (u16*)alloc((size_t)8192 * 1024 * 2);      // 16
  u16* WtF2   = (u16*)alloc((size_t)1024 * 4096 * 2);      // 8
  float* prep = (float*)alloc((size_t)16 * 256 * PREPSZ * 4);  // 36 MiB
  unsigned* masks = (unsigned*)alloc((size_t)16 * 64 * 64 * 4);  // 1 MiB => ~192 MiB total

  // weight transposes (f32 -> bf16, Bt = [N,K] k-contiguous)
  ktrans<<<dim3(16, 32), 256, 0, stream>>>(Wq, WtX + (size_t)0 * 512 * 1024, 1024, 512);
  ktrans<<<dim3(16, 32), 256, 0, stream>>>(Wk, WtX + (size_t)1 * 512 * 1024, 1024, 512);
  ktrans<<<dim3(16, 32), 256, 0, stream>>>(Wv, WtX + (size_t)2 * 512 * 1024, 1024, 512);
  ktrans<<<dim3(16, 32), 256, 0, stream>>>(Wspike, WtX + (size_t)3 * 512 * 1024, 1024, 512);
  ktrans<<<dim3(32, 16), 256, 0, stream>>>(Wo, WtO, 512, 1024);
  ktrans<<<dim3(128, 32), 256, 0, stream>>>(Wff1, WtFF, 1024, 4096);
  ktrans<<<dim3(128, 32), 256, 0, stream>>>(Wff3, WtFF + (size_t)4096 * 1024, 1024, 4096);
  ktrans<<<dim3(32, 128), 256, 0, stream>>>(Wff2, WtF2, 4096, 1024);

  // front end
  krms<<<BTt, 256, 0, stream>>>(x, norm_in_w, h, 0);
  kconv<<<BTt * DD / 256, 256, 0, stream>>>(h, conv_w, conv_b, hc);

  // QKVD projection (MFMA): -> X1 f32 [4096,2048]
  kmfma<0><<<dim3(16, 32), 256, 0, stream>>>(
      hc, 1024, WtX, X1, 2048, BTt, 2048, 1024, nullptr, nullptr, nullptr, 0);

  // small projections (f32 compute)
  kgemm<<<dim3(1, 64), 256, 0, stream>>>(hc, 1, Wau, bau, au, BTt, 64, DD, 1);
  kgemm<<<dim3(8, 64), 256, 0, stream>>>(au, 0, Wad, bad_, ab, BTt, HKk, 64, 0);
  kgemm<<<dim3(1, 64), 256, 0, stream>>>(hc, 1, Wbeta, bbeta, bb, BTt, HH, DD, 0);

  kl2norm<<<BTt * 16 / 4, 256, 0, stream>>>(X1);
  klifA<<<BB * HH, 64, 0, stream>>>(X1 + 1536, 2048, masks);
  klifB<<<BB * HH * 16, 64, 0, stream>>>(masks, ab, bb, asp, bsp, alph, beta);
  kprep<<<16 * 256, 64, 0, stream>>>(X1, alph, beta, prep);
  kscan2<<<16 * 8, 64, 0, stream>>>(prep, yat);
  kheadnorm<<<BTt * HH / 4, 256, 0, stream>>>(yat, hnw, yat_bf);

  // gate path (f32)
  kgemm<<<dim3(1, 64), 256, 0, stream>>>(x, 0, Wu1, bu1, u1, BTt, 64, DD, 1);
  kgemm<<<dim3(16, 64), 256, 0, stream>>>(u1, 0, Wu2, bu2, gate, BTt, DD, 64, 2);

  // y2 = x + (yat @ Wo) * gate   (MFMA, f32 out)
  kmfma<2><<<dim3(8, 32), 256, 0, stream>>>(
      yat_bf, 512, WtO, y2, 1024, BTt, 1024, 512, x, gate, nullptr, 0);

  // FFN (MFMA)
  krms<<<BTt, 256, 0, stream>>>(y2, ffw, z_bf, 1);
  kmfma<1><<<dim3(64, 32), 256, 0, stream>>>(
      z_bf, 1024, WtFF, f_bf, 8192, BTt, 8192, 1024, nullptr, nullptr, nullptr, 4096);
  kmulg<<<BTt * 4096 / 8 / 256, 256, 0, stream>>>(f_bf);
  kmfma<3><<<dim3(8, 32), 256, 0, stream>>>(
      f_bf, 8192, WtF2, d_out, 1024, BTt, 1024, 4096, nullptr, nullptr, y2, 0);
}